// Round 1
// baseline (1796.105 us; speedup 1.0000x reference)
//
#include <hip/hip_runtime.h>
#include <hip/hip_bf16.h>
#include <math.h>

#define NN 50000
#define EE 800000
#define ET 850000
#define NEG 0.2f

// ---- helpers ----
static __device__ __forceinline__ unsigned fenc(float f){
  unsigned u = __float_as_uint(f);
  return (u & 0x80000000u) ? ~u : (u | 0x80000000u);
}
static __device__ __forceinline__ float fdec(unsigned u){
  return (u & 0x80000000u) ? __uint_as_float(u ^ 0x80000000u) : __uint_as_float(~u);
}
static __device__ __forceinline__ float lrelu(float x){ return x > 0.f ? x : NEG * x; }
static __device__ __forceinline__ void edge_sd(const int* __restrict__ ei, int e, int& s, int& d){
  if (e < EE){ s = ei[e]; d = ei[e + EE]; } else { s = e - EE; d = s; }
}

// ---- GAT1: h1 = x @ W1 (512->48), e_src1/e_dst1 per node ----
__global__ __launch_bounds__(256) void k_gat1_gemm(
    const float* __restrict__ x, const float* __restrict__ W1,
    const float* __restrict__ a_src, const float* __restrict__ a_dst,
    float* __restrict__ h1, float* __restrict__ es1, float* __restrict__ ed1)
{
  __shared__ float xs[16][512];
  __shared__ float hs[16][48];
  int t = threadIdx.x;
  int n0 = blockIdx.x * 16;
  const float4* xv = (const float4*)(x + (size_t)n0 * 512);
  float4* xsv = (float4*)&xs[0][0];
#pragma unroll
  for (int p = 0; p < 8; ++p) xsv[t + p * 256] = xv[t + p * 256];
  __syncthreads();
#pragma unroll
  for (int p = 0; p < 3; ++p){
    int idx = t + p * 256;
    int node = idx / 48, o = idx % 48;
    const float* xr = xs[node];
    float acc = 0.f;
    for (int k = 0; k < 512; ++k) acc = fmaf(xr[k], W1[k * 48 + o], acc);
    h1[(size_t)(n0 + node) * 48 + o] = acc;
    hs[node][o] = acc;
  }
  __syncthreads();
  if (t < 96){
    int which = t / 48;           // 0 = src, 1 = dst
    int idx = t % 48;
    int node = idx / 3, h = idx % 3;
    const float* av = which ? a_dst : a_src;
    float acc = 0.f;
#pragma unroll
    for (int c = 0; c < 16; ++c) acc = fmaf(hs[node][h * 16 + c], av[h * 16 + c], acc);
    (which ? ed1 : es1)[(size_t)(n0 + node) * 3 + h] = acc;
  }
}

// ---- edge pass: segment max (3 heads) + degree count ----
__global__ __launch_bounds__(256) void k_edge_max1(const int* __restrict__ ei,
    const float* __restrict__ es1, const float* __restrict__ ed1,
    unsigned* __restrict__ m1, float* __restrict__ deg)
{
  int e = blockIdx.x * 256 + threadIdx.x;
  if (e >= ET) return;
  int s, d; edge_sd(ei, e, s, d);
  atomicAdd(deg + d, 1.0f);
#pragma unroll
  for (int h = 0; h < 3; ++h){
    float v = lrelu(es1[(size_t)s * 3 + h] + ed1[(size_t)d * 3 + h]);
    atomicMax(m1 + (size_t)d * 3 + h, fenc(v));
  }
}

__global__ __launch_bounds__(256) void k_edge_sum1(const int* __restrict__ ei,
    const float* __restrict__ es1, const float* __restrict__ ed1,
    const unsigned* __restrict__ m1, float* __restrict__ s1)
{
  int e = blockIdx.x * 256 + threadIdx.x;
  if (e >= ET) return;
  int s, d; edge_sd(ei, e, s, d);
#pragma unroll
  for (int h = 0; h < 3; ++h){
    float v = lrelu(es1[(size_t)s * 3 + h] + ed1[(size_t)d * 3 + h]);
    atomicAdd(s1 + (size_t)d * 3 + h, __expf(v - fdec(m1[(size_t)d * 3 + h])));
  }
}

// 16 threads per edge; lane c covers feature c of each of 3 heads
__global__ __launch_bounds__(256) void k_edge_scatter1(const int* __restrict__ ei,
    const float* __restrict__ es1, const float* __restrict__ ed1,
    const unsigned* __restrict__ m1, const float* __restrict__ s1,
    const float* __restrict__ h1, float* __restrict__ o1)
{
  int t = threadIdx.x;
  int e = blockIdx.x * 16 + (t >> 4);
  int c = t & 15;
  if (e >= ET) return;
  int s, d; edge_sd(ei, e, s, d);
#pragma unroll
  for (int h = 0; h < 3; ++h){
    float v = lrelu(es1[(size_t)s * 3 + h] + ed1[(size_t)d * 3 + h]);
    float w = __expf(v - fdec(m1[(size_t)d * 3 + h])) / s1[(size_t)d * 3 + h];
    atomicAdd(o1 + (size_t)d * 48 + h * 16 + c, h1[(size_t)s * 48 + h * 16 + c] * w);
  }
}

// ---- elu(o1+b1) in place; deg -> rsqrt(max(deg,1)) in place ----
__global__ __launch_bounds__(256) void k_elu_dinv(float* __restrict__ o1,
    const float* __restrict__ b1, float* __restrict__ deg)
{
  int i = blockIdx.x * 256 + threadIdx.x;
  if (i < NN * 48){
    float v = o1[i] + b1[i % 48];
    o1[i] = v > 0.f ? v : expm1f(v);
  }
  if (i < NN){
    deg[i] = rsqrtf(fmaxf(deg[i], 1.0f));
  }
}

// ---- GAT2: h2 = h1b @ W2 (48->128), e_src2/e_dst2 ----
__global__ __launch_bounds__(256) void k_gat2_gemm(const float* __restrict__ h1b,
    const float* __restrict__ W2, const float* __restrict__ a_src, const float* __restrict__ a_dst,
    float* __restrict__ h2, float* __restrict__ es2, float* __restrict__ ed2)
{
  __shared__ float rs[2][48];
  __shared__ float part[2][2][2];
  int t = threadIdx.x;
  int n0 = blockIdx.x * 2;
  if (t < 96) rs[t / 48][t % 48] = h1b[(size_t)n0 * 48 + t];
  __syncthreads();
  int ln = t >> 7;
  int j = t & 127;
  float acc = 0.f;
#pragma unroll
  for (int k = 0; k < 48; ++k) acc = fmaf(rs[ln][k], W2[k * 128 + j], acc);
  h2[(size_t)(n0 + ln) * 128 + j] = acc;
  float vs = acc * a_src[j];
  float vd = acc * a_dst[j];
#pragma unroll
  for (int off = 32; off; off >>= 1){ vs += __shfl_xor(vs, off); vd += __shfl_xor(vd, off); }
  int wv = (t >> 6) & 1;
  if ((t & 63) == 0){ part[ln][wv][0] = vs; part[ln][wv][1] = vd; }
  __syncthreads();
  if ((t & 127) == 0){
    es2[n0 + ln] = part[ln][0][0] + part[ln][1][0];
    ed2[n0 + ln] = part[ln][0][1] + part[ln][1][1];
  }
}

__global__ __launch_bounds__(256) void k_edge_max2(const int* __restrict__ ei,
    const float* __restrict__ es2, const float* __restrict__ ed2, unsigned* __restrict__ m2)
{
  int e = blockIdx.x * 256 + threadIdx.x;
  if (e >= ET) return;
  int s, d; edge_sd(ei, e, s, d);
  atomicMax(m2 + d, fenc(lrelu(es2[s] + ed2[d])));
}

__global__ __launch_bounds__(256) void k_edge_sum2(const int* __restrict__ ei,
    const float* __restrict__ es2, const float* __restrict__ ed2,
    const unsigned* __restrict__ m2, float* __restrict__ s2)
{
  int e = blockIdx.x * 256 + threadIdx.x;
  if (e >= ET) return;
  int s, d; edge_sd(ei, e, s, d);
  atomicAdd(s2 + d, __expf(lrelu(es2[s] + ed2[d]) - fdec(m2[d])));
}

// 128 threads per edge (2 edges / block)
__global__ __launch_bounds__(256) void k_edge_scatter2(const int* __restrict__ ei,
    const float* __restrict__ es2, const float* __restrict__ ed2,
    const unsigned* __restrict__ m2, const float* __restrict__ s2,
    const float* __restrict__ h2, float* __restrict__ o2)
{
  int t = threadIdx.x;
  int e = blockIdx.x * 2 + (t >> 7);
  int c = t & 127;
  if (e >= ET) return;
  int s, d; edge_sd(ei, e, s, d);
  float w = __expf(lrelu(es2[s] + ed2[d]) - fdec(m2[d])) / s2[d];
  atomicAdd(o2 + (size_t)d * 128 + c, h2[(size_t)s * 128 + c] * w);
}

// ---- log_softmax(o2 + b2) in place, 2 nodes / block ----
__global__ __launch_bounds__(256) void k_lsm(float* __restrict__ o2, const float* __restrict__ b2)
{
  __shared__ float pm[2][2], ps[2][2];
  int t = threadIdx.x;
  int ln = t >> 7;
  int j = t & 127;
  int n = blockIdx.x * 2 + ln;
  int wv = (t >> 6) & 1;
  float v = o2[(size_t)n * 128 + j] + b2[j];
  float m = v;
#pragma unroll
  for (int off = 32; off; off >>= 1) m = fmaxf(m, __shfl_xor(m, off));
  if ((t & 63) == 0) pm[ln][wv] = m;
  __syncthreads();
  m = fmaxf(pm[ln][0], pm[ln][1]);
  float ex = __expf(v - m);
  float sum = ex;
#pragma unroll
  for (int off = 32; off; off >>= 1) sum += __shfl_xor(sum, off);
  if ((t & 63) == 0) ps[ln][wv] = sum;
  __syncthreads();
  sum = ps[ln][0] + ps[ln][1];
  o2[(size_t)n * 128 + j] = v - m - __logf(sum);
}

// ---- generic 128x128 per-node GEMM; PRE=1: in' = relu(in + bpre) ----
template<int PRE>
__global__ __launch_bounds__(256) void k_gemm128(const float* __restrict__ in,
    const float* __restrict__ W, const float* __restrict__ bpre,
    const float* __restrict__ bpost, float* __restrict__ out)
{
  __shared__ float gs[8][128];
  int t = threadIdx.x;
  int n0 = blockIdx.x * 8;
#pragma unroll
  for (int p = 0; p < 4; ++p){
    int idx = t + p * 256;
    int node = idx >> 7, j = idx & 127;
    float v = in[(size_t)(n0 + node) * 128 + j];
    if (PRE){ v += bpre[j]; v = fmaxf(v, 0.f); }
    gs[node][j] = v;
  }
  __syncthreads();
#pragma unroll
  for (int p = 0; p < 4; ++p){
    int idx = t + p * 256;
    int node = idx >> 7, j = idx & 127;
    float acc = bpost ? bpost[j] : 0.f;
    for (int k = 0; k < 128; ++k) acc = fmaf(gs[node][k], W[k * 128 + j], acc);
    out[(size_t)(n0 + node) * 128 + j] = acc;
  }
}

// ---- GCN scatter: og[dst] += hg[src] * dinv[src]*dinv[dst] ----
__global__ __launch_bounds__(256) void k_gcn_scatter(const int* __restrict__ ei,
    const float* __restrict__ dinv, const float* __restrict__ hg, float* __restrict__ og)
{
  int t = threadIdx.x;
  int e = blockIdx.x * 2 + (t >> 7);
  int c = t & 127;
  if (e >= ET) return;
  int s, d; edge_sd(ei, e, s, d);
  float nrm = dinv[s] * dinv[d];
  atomicAdd(og + (size_t)d * 128 + c, hg[(size_t)s * 128 + c] * nrm);
}

extern "C" void kernel_launch(void* const* d_in, const int* in_sizes, int n_in,
                              void* d_out, int out_size, void* d_ws, size_t ws_size,
                              hipStream_t stream)
{
  const float* x   = (const float*)d_in[0];
  const int*   ei  = (const int*)d_in[1];
  const float* W1  = (const float*)d_in[2];
  const float* as1 = (const float*)d_in[3];
  const float* ad1 = (const float*)d_in[4];
  const float* b1  = (const float*)d_in[5];
  const float* W2  = (const float*)d_in[6];
  const float* as2 = (const float*)d_in[7];
  const float* ad2 = (const float*)d_in[8];
  const float* b2  = (const float*)d_in[9];
  const float* Wg  = (const float*)d_in[10];
  const float* bg  = (const float*)d_in[11];
  const float* Wl  = (const float*)d_in[12];
  const float* bl  = (const float*)d_in[13];
  float* out = (float*)d_out;

  float* ws = (float*)d_ws;
  const size_t n = NN;
  float* h1   = ws;                 // 48N
  float* h2   = ws + 48 * n;        // 128N (reused as hg)
  float* o1   = ws + 176 * n;       // 48N  zero
  float* o2   = ws + 224 * n;       // 128N zero (reused as g)
  float* og   = ws + 352 * n;       // 128N zero
  float* s1   = ws + 480 * n;       // 3N   zero
  float* s2   = ws + 483 * n;       // N    zero
  float* deg  = ws + 484 * n;       // N    zero (becomes dinv)
  unsigned* m1 = (unsigned*)(ws + 485 * n); // 3N zero (= encoded identity)
  unsigned* m2 = (unsigned*)(ws + 488 * n); // N  zero
  float* es1  = ws + 489 * n;       // 3N
  float* ed1  = ws + 492 * n;       // 3N
  float* es2  = ws + 495 * n;       // N
  float* ed2  = ws + 496 * n;       // N

  // zero block covers o1..m2
  hipMemsetAsync(ws + 176 * n, 0, 313 * n * sizeof(float), stream);

  const int egrid = (ET + 255) / 256;
  k_gat1_gemm<<<NN / 16, 256, 0, stream>>>(x, W1, as1, ad1, h1, es1, ed1);
  k_edge_max1<<<egrid, 256, 0, stream>>>(ei, es1, ed1, m1, deg);
  k_edge_sum1<<<egrid, 256, 0, stream>>>(ei, es1, ed1, m1, s1);
  k_edge_scatter1<<<ET / 16, 256, 0, stream>>>(ei, es1, ed1, m1, s1, h1, o1);
  k_elu_dinv<<<(NN * 48 + 255) / 256, 256, 0, stream>>>(o1, b1, deg);
  k_gat2_gemm<<<NN / 2, 256, 0, stream>>>(o1, W2, as2, ad2, h2, es2, ed2);
  k_edge_max2<<<egrid, 256, 0, stream>>>(ei, es2, ed2, m2);
  k_edge_sum2<<<egrid, 256, 0, stream>>>(ei, es2, ed2, m2, s2);
  k_edge_scatter2<<<ET / 2, 256, 0, stream>>>(ei, es2, ed2, m2, s2, h2, o2);
  k_lsm<<<NN / 2, 256, 0, stream>>>(o2, b2);
  k_gemm128<0><<<NN / 8, 256, 0, stream>>>(o2, Wg, nullptr, nullptr, h2);
  k_gcn_scatter<<<ET / 2, 256, 0, stream>>>(ei, deg, h2, og);
  k_gemm128<1><<<NN / 8, 256, 0, stream>>>(og, Wl, bg, bl, out);
}

// Round 2
// 1039.218 us; speedup vs baseline: 1.7283x; 1.7283x over previous
//
#include <hip/hip_runtime.h>
#include <hip/hip_bf16.h>
#include <math.h>

#define NN 50000
#define EE 800000
#define ET 850000
#define NEG 0.2f

static __device__ __forceinline__ float lrelu(float x){ return x > 0.f ? x : NEG * x; }
static __device__ __forceinline__ void edge_sd(const int* __restrict__ ei, int e, int& s, int& d){
  if (e < EE){ s = ei[e]; d = ei[e + EE]; } else { s = e - EE; d = s; }
}

// ---- CSR build: histogram ----
__global__ __launch_bounds__(256) void k_hist(const int* __restrict__ ei, int* __restrict__ deg_i)
{
  int e = blockIdx.x * 256 + threadIdx.x;
  if (e >= ET) return;
  int s, d; edge_sd(ei, e, s, d);
  atomicAdd(deg_i + d, 1);
}

// ---- single-block scan over 50000 degrees -> exclusive row_start; also dinv ----
__global__ __launch_bounds__(1024) void k_scan(const int* __restrict__ deg_i,
    int* __restrict__ row_start, float* __restrict__ dinv)
{
  __shared__ int bs[1024];
  int t = threadIdx.x;
  const int CH = (NN + 1023) / 1024;   // 49
  int base = t * CH;
  int sum = 0;
  for (int i = 0; i < CH; ++i){ int idx = base + i; if (idx < NN) sum += deg_i[idx]; }
  bs[t] = sum; __syncthreads();
  for (int off = 1; off < 1024; off <<= 1){
    int add = (t >= off) ? bs[t - off] : 0;
    __syncthreads();
    bs[t] += add;
    __syncthreads();
  }
  int run = (t == 0) ? 0 : bs[t - 1];
  for (int i = 0; i < CH; ++i){
    int idx = base + i;
    if (idx < NN){
      int dv = deg_i[idx];
      row_start[idx] = run;
      dinv[idx] = rsqrtf(fmaxf((float)dv, 1.0f));
      run += dv;
    }
  }
  if (t == 0) row_start[NN] = bs[1023];
}

// ---- CSR fill: csr[row_start[d] + pos] = src ----
__global__ __launch_bounds__(256) void k_fill(const int* __restrict__ ei,
    const int* __restrict__ row_start, int* __restrict__ cur, int* __restrict__ csr)
{
  int e = blockIdx.x * 256 + threadIdx.x;
  if (e >= ET) return;
  int s, d; edge_sd(ei, e, s, d);
  int pos = atomicAdd(cur + d, 1);
  csr[row_start[d] + pos] = s;
}

// ---- GAT1: h1 = x @ W1 (512->48), e_src1/e_dst1 per node ----
__global__ __launch_bounds__(256) void k_gat1_gemm(
    const float* __restrict__ x, const float* __restrict__ W1,
    const float* __restrict__ a_src, const float* __restrict__ a_dst,
    float* __restrict__ h1, float* __restrict__ es1, float* __restrict__ ed1)
{
  __shared__ float xs[16][512];
  __shared__ float hs[16][48];
  int t = threadIdx.x;
  int n0 = blockIdx.x * 16;
  const float4* xv = (const float4*)(x + (size_t)n0 * 512);
  float4* xsv = (float4*)&xs[0][0];
#pragma unroll
  for (int p = 0; p < 8; ++p) xsv[t + p * 256] = xv[t + p * 256];
  __syncthreads();
#pragma unroll
  for (int p = 0; p < 3; ++p){
    int idx = t + p * 256;
    int node = idx / 48, o = idx % 48;
    const float* xr = xs[node];
    float acc = 0.f;
    for (int k = 0; k < 512; ++k) acc = fmaf(xr[k], W1[k * 48 + o], acc);
    h1[(size_t)(n0 + node) * 48 + o] = acc;
    hs[node][o] = acc;
  }
  __syncthreads();
  if (t < 96){
    int which = t / 48;           // 0 = src, 1 = dst
    int idx = t % 48;
    int node = idx / 3, h = idx % 3;
    const float* av = which ? a_dst : a_src;
    float acc = 0.f;
#pragma unroll
    for (int c = 0; c < 16; ++c) acc = fmaf(hs[node][h * 16 + c], av[h * 16 + c], acc);
    (which ? ed1 : es1)[(size_t)(n0 + node) * 3 + h] = acc;
  }
}

// ---- GAT1 aggregate: one wave per dst node, online softmax, fused +b1 + ELU ----
__global__ __launch_bounds__(256) void k_gat1_agg(
    const int* __restrict__ csr, const int* __restrict__ row_start,
    const float* __restrict__ es1, const float* __restrict__ ed1,
    const float* __restrict__ h1, const float* __restrict__ b1,
    float* __restrict__ o1)
{
  int d = (blockIdx.x * 256 + threadIdx.x) >> 6;
  int lane = threadIdx.x & 63;
  if (d >= NN) return;
  bool act = lane < 48;
  int hd = act ? (lane >> 4) : 0;
  int beg = row_start[d], end = row_start[d + 1];
  float edv = ed1[(size_t)d * 3 + hd];
  float m = -INFINITY, sum = 0.f, acc = 0.f;
  for (int i = beg; i < end; ++i){
    int s = csr[i];
    float e = lrelu(es1[(size_t)s * 3 + hd] + edv);
    float mn = fmaxf(m, e);
    float sc = __expf(m - mn);
    float w  = __expf(e - mn);
    sum = sum * sc + w;
    float hv = act ? h1[(size_t)s * 48 + lane] : 0.f;
    acc = acc * sc + hv * w;
    m = mn;
  }
  if (act){
    float v = acc / sum + b1[lane];
    o1[(size_t)d * 48 + lane] = v > 0.f ? v : expm1f(v);
  }
}

// ---- GAT2: h2 = o1 @ W2 (48->128), e_src2/e_dst2 ----
__global__ __launch_bounds__(256) void k_gat2_gemm(const float* __restrict__ h1b,
    const float* __restrict__ W2, const float* __restrict__ a_src, const float* __restrict__ a_dst,
    float* __restrict__ h2, float* __restrict__ es2, float* __restrict__ ed2)
{
  __shared__ float rs[2][48];
  __shared__ float part[2][2][2];
  int t = threadIdx.x;
  int n0 = blockIdx.x * 2;
  if (t < 96) rs[t / 48][t % 48] = h1b[(size_t)n0 * 48 + t];
  __syncthreads();
  int ln = t >> 7;
  int j = t & 127;
  float acc = 0.f;
#pragma unroll
  for (int k = 0; k < 48; ++k) acc = fmaf(rs[ln][k], W2[k * 128 + j], acc);
  h2[(size_t)(n0 + ln) * 128 + j] = acc;
  float vs = acc * a_src[j];
  float vd = acc * a_dst[j];
#pragma unroll
  for (int off = 32; off; off >>= 1){ vs += __shfl_xor(vs, off); vd += __shfl_xor(vd, off); }
  int wv = (t >> 6) & 1;
  if ((t & 63) == 0){ part[ln][wv][0] = vs; part[ln][wv][1] = vd; }
  __syncthreads();
  if ((t & 127) == 0){
    es2[n0 + ln] = part[ln][0][0] + part[ln][1][0];
    ed2[n0 + ln] = part[ln][0][1] + part[ln][1][1];
  }
}

// ---- GAT2 aggregate + fused +b2 + log_softmax: one wave per node, 2 feats/lane ----
__global__ __launch_bounds__(256) void k_gat2_agg(
    const int* __restrict__ csr, const int* __restrict__ row_start,
    const float* __restrict__ es2, const float* __restrict__ ed2,
    const float* __restrict__ h2, const float* __restrict__ b2,
    float* __restrict__ o2)
{
  int d = (blockIdx.x * 256 + threadIdx.x) >> 6;
  int lane = threadIdx.x & 63;
  if (d >= NN) return;
  int beg = row_start[d], end = row_start[d + 1];
  float edv = ed2[d];
  float m = -INFINITY, sum = 0.f, a0 = 0.f, a1 = 0.f;
  for (int i = beg; i < end; ++i){
    int s = csr[i];
    float e = lrelu(es2[s] + edv);
    float mn = fmaxf(m, e);
    float sc = __expf(m - mn);
    float w  = __expf(e - mn);
    sum = sum * sc + w;
    float2 hv = *(const float2*)(h2 + (size_t)s * 128 + 2 * lane);
    a0 = a0 * sc + hv.x * w;
    a1 = a1 * sc + hv.y * w;
    m = mn;
  }
  float v0 = a0 / sum + b2[2 * lane];
  float v1 = a1 / sum + b2[2 * lane + 1];
  // wave log_softmax over the 128 features
  float mx = fmaxf(v0, v1);
#pragma unroll
  for (int off = 32; off; off >>= 1) mx = fmaxf(mx, __shfl_xor(mx, off));
  float es = __expf(v0 - mx) + __expf(v1 - mx);
#pragma unroll
  for (int off = 32; off; off >>= 1) es += __shfl_xor(es, off);
  float lse = mx + __logf(es);
  float2 ov; ov.x = v0 - lse; ov.y = v1 - lse;
  *(float2*)(o2 + (size_t)d * 128 + 2 * lane) = ov;
}

// ---- GCN aggregate: one wave per node ----
__global__ __launch_bounds__(256) void k_gcn_agg(
    const int* __restrict__ csr, const int* __restrict__ row_start,
    const float* __restrict__ dinv, const float* __restrict__ hg,
    float* __restrict__ og)
{
  int d = (blockIdx.x * 256 + threadIdx.x) >> 6;
  int lane = threadIdx.x & 63;
  if (d >= NN) return;
  int beg = row_start[d], end = row_start[d + 1];
  float a0 = 0.f, a1 = 0.f;
  for (int i = beg; i < end; ++i){
    int s = csr[i];
    float ds = dinv[s];
    float2 hv = *(const float2*)(hg + (size_t)s * 128 + 2 * lane);
    a0 = fmaf(hv.x, ds, a0);
    a1 = fmaf(hv.y, ds, a1);
  }
  float dd = dinv[d];
  float2 ov; ov.x = a0 * dd; ov.y = a1 * dd;
  *(float2*)(og + (size_t)d * 128 + 2 * lane) = ov;
}

// ---- generic 128x128 per-node GEMM; PRE=1: in' = relu(in + bpre) ----
template<int PRE>
__global__ __launch_bounds__(256) void k_gemm128(const float* __restrict__ in,
    const float* __restrict__ W, const float* __restrict__ bpre,
    const float* __restrict__ bpost, float* __restrict__ out)
{
  __shared__ float gs[8][128];
  int t = threadIdx.x;
  int n0 = blockIdx.x * 8;
#pragma unroll
  for (int p = 0; p < 4; ++p){
    int idx = t + p * 256;
    int node = idx >> 7, j = idx & 127;
    float v = in[(size_t)(n0 + node) * 128 + j];
    if (PRE){ v += bpre[j]; v = fmaxf(v, 0.f); }
    gs[node][j] = v;
  }
  __syncthreads();
#pragma unroll
  for (int p = 0; p < 4; ++p){
    int idx = t + p * 256;
    int node = idx >> 7, j = idx & 127;
    float acc = bpost ? bpost[j] : 0.f;
    for (int k = 0; k < 128; ++k) acc = fmaf(gs[node][k], W[k * 128 + j], acc);
    out[(size_t)(n0 + node) * 128 + j] = acc;
  }
}

extern "C" void kernel_launch(void* const* d_in, const int* in_sizes, int n_in,
                              void* d_out, int out_size, void* d_ws, size_t ws_size,
                              hipStream_t stream)
{
  const float* x   = (const float*)d_in[0];
  const int*   ei  = (const int*)d_in[1];
  const float* W1  = (const float*)d_in[2];
  const float* as1 = (const float*)d_in[3];
  const float* ad1 = (const float*)d_in[4];
  const float* b1  = (const float*)d_in[5];
  const float* W2  = (const float*)d_in[6];
  const float* as2 = (const float*)d_in[7];
  const float* ad2 = (const float*)d_in[8];
  const float* b2  = (const float*)d_in[9];
  const float* Wg  = (const float*)d_in[10];
  const float* bg  = (const float*)d_in[11];
  const float* Wl  = (const float*)d_in[12];
  const float* bl  = (const float*)d_in[13];
  float* out = (float*)d_out;

  float* ws = (float*)d_ws;
  const size_t n = NN;
  float* h1   = ws;                 // 48N
  float* h2   = ws + 48 * n;        // 128N (reused as hg)
  float* o1   = ws + 176 * n;       // 48N
  float* o2   = ws + 224 * n;       // 128N (lsm out; later reused as og)
  float* es1  = ws + 352 * n;       // 3N
  float* ed1  = ws + 355 * n;       // 3N
  float* es2  = ws + 358 * n;       // N
  float* ed2  = ws + 359 * n;       // N
  float* dinv = ws + 360 * n;       // N
  int* ints   = (int*)(ws + 361 * n);
  int* deg_i     = ints;            // N   (zeroed)
  int* cur       = ints + n;        // N   (zeroed)
  int* row_start = ints + 2 * n;    // N+1
  int* csr       = ints + 3 * n + 1;// ET
  float* og = o2;                   // overwrite o2 after gemm128<0> consumed it

  hipMemsetAsync(deg_i, 0, 2 * n * sizeof(int), stream);

  const int egrid = (ET + 255) / 256;
  const int wgrid = (NN * 64) / 256;   // one wave per node
  k_hist<<<egrid, 256, 0, stream>>>(ei, deg_i);
  k_scan<<<1, 1024, 0, stream>>>(deg_i, row_start, dinv);
  k_fill<<<egrid, 256, 0, stream>>>(ei, row_start, cur, csr);
  k_gat1_gemm<<<NN / 16, 256, 0, stream>>>(x, W1, as1, ad1, h1, es1, ed1);
  k_gat1_agg<<<wgrid, 256, 0, stream>>>(csr, row_start, es1, ed1, h1, b1, o1);
  k_gat2_gemm<<<NN / 2, 256, 0, stream>>>(o1, W2, as2, ad2, h2, es2, ed2);
  k_gat2_agg<<<wgrid, 256, 0, stream>>>(csr, row_start, es2, ed2, h2, b2, o2);
  k_gemm128<0><<<NN / 8, 256, 0, stream>>>(o2, Wg, nullptr, nullptr, h2);
  k_gcn_agg<<<wgrid, 256, 0, stream>>>(csr, row_start, dinv, h2, og);
  k_gemm128<1><<<NN / 8, 256, 0, stream>>>(og, Wl, bg, bl, out);
}

// Round 3
// 683.620 us; speedup vs baseline: 2.6273x; 1.5202x over previous
//
#include <hip/hip_runtime.h>
#include <hip/hip_bf16.h>
#include <math.h>

#define NN 50000
#define EE 800000
#define ET 850000
#define NEG 0.2f

static __device__ __forceinline__ float lrelu(float x){ return x > 0.f ? x : NEG * x; }
static __device__ __forceinline__ void edge_sd(const int* __restrict__ ei, int e, int& s, int& d){
  if (e < EE){ s = ei[e]; d = ei[e + EE]; } else { s = e - EE; d = s; }
}

// ---- CSR build ----
__global__ __launch_bounds__(256) void k_hist(const int* __restrict__ ei, int* __restrict__ deg_i)
{
  int e = blockIdx.x * 256 + threadIdx.x;
  if (e >= ET) return;
  int s, d; edge_sd(ei, e, s, d);
  atomicAdd(deg_i + d, 1);
}

__global__ __launch_bounds__(1024) void k_scan(const int* __restrict__ deg_i,
    int* __restrict__ row_start, float* __restrict__ dinv)
{
  __shared__ int bs[1024];
  int t = threadIdx.x;
  const int CH = (NN + 1023) / 1024;   // 49
  int base = t * CH;
  int sum = 0;
  for (int i = 0; i < CH; ++i){ int idx = base + i; if (idx < NN) sum += deg_i[idx]; }
  bs[t] = sum; __syncthreads();
  for (int off = 1; off < 1024; off <<= 1){
    int add = (t >= off) ? bs[t - off] : 0;
    __syncthreads();
    bs[t] += add;
    __syncthreads();
  }
  int run = (t == 0) ? 0 : bs[t - 1];
  for (int i = 0; i < CH; ++i){
    int idx = base + i;
    if (idx < NN){
      int dv = deg_i[idx];
      row_start[idx] = run;
      dinv[idx] = rsqrtf(fmaxf((float)dv, 1.0f));
      run += dv;
    }
  }
  if (t == 0) row_start[NN] = bs[1023];
}

__global__ __launch_bounds__(256) void k_fill(const int* __restrict__ ei,
    const int* __restrict__ row_start, int* __restrict__ cur, int* __restrict__ csr)
{
  int e = blockIdx.x * 256 + threadIdx.x;
  if (e >= ET) return;
  int s, d; edge_sd(ei, e, s, d);
  int pos = atomicAdd(cur + d, 1);
  csr[row_start[d] + pos] = s;
}

// ---- GAT1 GEMM: h1[50000x48] = x[50000x512] @ W1[512x48], fp32 register-tiled ----
// block: 128 nodes x 48 outs, K-tile 64, micro 8m x 3n, 256 thr (tx=16 n-groups, ty=16 m-groups)
__global__ __launch_bounds__(256) void k_gat1_gemm(
    const float* __restrict__ x, const float* __restrict__ W1, float* __restrict__ h1)
{
  __shared__ float At[64][132];   // [k][node]
  __shared__ float Bs[64][52];    // [k][out]
  int t = threadIdx.x;
  int tx = t & 15, ty = t >> 4;
  int n0 = blockIdx.x * 128;
  float acc[8][3] = {};
  for (int kt = 0; kt < 512; kt += 64){
    __syncthreads();
    // stage x tile (128x64), coalesced float4, transpose into At
#pragma unroll
    for (int p = 0; p < 8; ++p){
      int f = t + p * 256;
      int node = f >> 4, kq = f & 15;
      float4 v = make_float4(0.f, 0.f, 0.f, 0.f);
      int gn = n0 + node;
      if (gn < NN) v = *(const float4*)(x + (size_t)gn * 512 + kt + kq * 4);
      At[kq * 4 + 0][node] = v.x; At[kq * 4 + 1][node] = v.y;
      At[kq * 4 + 2][node] = v.z; At[kq * 4 + 3][node] = v.w;
    }
    // stage W1 rows kt..kt+63 (64x48)
#pragma unroll
    for (int p = 0; p < 3; ++p){
      int f = t + p * 256;
      int k = f / 12, oq = f % 12;
      *(float4*)&Bs[k][oq * 4] = *(const float4*)(W1 + (size_t)(kt + k) * 48 + oq * 4);
    }
    __syncthreads();
#pragma unroll 4
    for (int k = 0; k < 64; ++k){
      float4 a0 = *(const float4*)&At[k][ty * 8];
      float4 a1 = *(const float4*)&At[k][ty * 8 + 4];
      float b0 = Bs[k][tx * 3 + 0], b1 = Bs[k][tx * 3 + 1], b2 = Bs[k][tx * 3 + 2];
      float av[8] = {a0.x, a0.y, a0.z, a0.w, a1.x, a1.y, a1.z, a1.w};
#pragma unroll
      for (int i = 0; i < 8; ++i){
        acc[i][0] = fmaf(av[i], b0, acc[i][0]);
        acc[i][1] = fmaf(av[i], b1, acc[i][1]);
        acc[i][2] = fmaf(av[i], b2, acc[i][2]);
      }
    }
  }
#pragma unroll
  for (int i = 0; i < 8; ++i){
    int gn = n0 + ty * 8 + i;
    if (gn < NN){
      float* o = h1 + (size_t)gn * 48 + tx * 3;
      o[0] = acc[i][0]; o[1] = acc[i][1]; o[2] = acc[i][2];
    }
  }
}

// ---- es1/ed1: per-node per-head dots of h1 with a_src1/a_dst1 ----
__global__ __launch_bounds__(256) void k_att1(const float* __restrict__ h1,
    const float* __restrict__ as1, const float* __restrict__ ad1,
    float* __restrict__ es1, float* __restrict__ ed1)
{
  int n = (blockIdx.x * 256 + threadIdx.x) >> 6;
  int lane = threadIdx.x & 63;
  if (n >= NN) return;
  float ps = 0.f, pd = 0.f;
  if (lane < 48){
    float v = h1[(size_t)n * 48 + lane];
    ps = v * as1[lane]; pd = v * ad1[lane];
  }
#pragma unroll
  for (int off = 8; off; off >>= 1){
    ps += __shfl_xor(ps, off, 16);
    pd += __shfl_xor(pd, off, 16);
  }
  if (lane < 48 && (lane & 15) == 0){
    es1[(size_t)n * 3 + (lane >> 4)] = ps;
    ed1[(size_t)n * 3 + (lane >> 4)] = pd;
  }
}

// ---- GAT1 aggregate: one wave/node, online softmax, unroll-2, fused +b1 + ELU ----
__global__ __launch_bounds__(256) void k_gat1_agg(
    const int* __restrict__ csr, const int* __restrict__ row_start,
    const float* __restrict__ es1, const float* __restrict__ ed1,
    const float* __restrict__ h1, const float* __restrict__ b1,
    float* __restrict__ o1)
{
  int dn = (blockIdx.x * 256 + threadIdx.x) >> 6;
  int lane = threadIdx.x & 63;
  if (dn >= NN) return;
  bool act = lane < 48;
  int hd = act ? (lane >> 4) : 0;
  int beg = row_start[dn], end = row_start[dn + 1];
  float edv = ed1[(size_t)dn * 3 + hd];
  float m = -INFINITY, sum = 0.f, acc = 0.f;
  int i = beg;
  for (; i + 1 < end; i += 2){
    int s0 = csr[i], s1 = csr[i + 1];
    float e0 = lrelu(es1[(size_t)s0 * 3 + hd] + edv);
    float e1 = lrelu(es1[(size_t)s1 * 3 + hd] + edv);
    float h0 = act ? h1[(size_t)s0 * 48 + lane] : 0.f;
    float h1v = act ? h1[(size_t)s1 * 48 + lane] : 0.f;
    float mn = fmaxf(m, fmaxf(e0, e1));
    float sc = __expf(m - mn), w0 = __expf(e0 - mn), w1 = __expf(e1 - mn);
    sum = sum * sc + w0 + w1;
    acc = acc * sc + h0 * w0 + h1v * w1;
    m = mn;
  }
  if (i < end){
    int s0 = csr[i];
    float e0 = lrelu(es1[(size_t)s0 * 3 + hd] + edv);
    float h0 = act ? h1[(size_t)s0 * 48 + lane] : 0.f;
    float mn = fmaxf(m, e0);
    float sc = __expf(m - mn), w0 = __expf(e0 - mn);
    sum = sum * sc + w0;
    acc = acc * sc + h0 * w0;
  }
  if (act){
    float v = acc / sum + b1[lane];
    o1[(size_t)dn * 48 + lane] = v > 0.f ? v : expm1f(v);
  }
}

// ---- GAT2 GEMM: h2[50000x128] = o1[50000x48] @ W2[48x128]; fused es2/ed2 ----
// block: 64 nodes, micro 4m x 8n
__global__ __launch_bounds__(256) void k_gat2_gemm(const float* __restrict__ o1,
    const float* __restrict__ W2, const float* __restrict__ as2, const float* __restrict__ ad2,
    float* __restrict__ h2, float* __restrict__ es2, float* __restrict__ ed2)
{
  __shared__ float At[48][68];
  __shared__ float Ws[48][128];
  int t = threadIdx.x, tx = t & 15, ty = t >> 4;
  int n0 = blockIdx.x * 64;
#pragma unroll
  for (int p = 0; p < 3; ++p){
    int f = t + p * 256;           // 768 float4 = 64 rows x 12
    int node = f / 12, kq = f % 12;
    float4 v = make_float4(0.f, 0.f, 0.f, 0.f);
    if (n0 + node < NN) v = *(const float4*)(o1 + (size_t)(n0 + node) * 48 + kq * 4);
    At[kq * 4 + 0][node] = v.x; At[kq * 4 + 1][node] = v.y;
    At[kq * 4 + 2][node] = v.z; At[kq * 4 + 3][node] = v.w;
  }
#pragma unroll
  for (int p = 0; p < 6; ++p){
    int f = t + p * 256;           // 1536 float4 = 48 rows x 32
    int k = f >> 5, cq = f & 31;
    *(float4*)&Ws[k][cq * 4] = *(const float4*)(W2 + (size_t)k * 128 + cq * 4);
  }
  __syncthreads();
  float acc[4][8] = {};
#pragma unroll 4
  for (int k = 0; k < 48; ++k){
    float4 a  = *(const float4*)&At[k][ty * 4];
    float4 c0 = *(const float4*)&Ws[k][tx * 4];
    float4 c1 = *(const float4*)&Ws[k][tx * 4 + 64];
    float av[4] = {a.x, a.y, a.z, a.w};
    float bv[8] = {c0.x, c0.y, c0.z, c0.w, c1.x, c1.y, c1.z, c1.w};
#pragma unroll
    for (int i = 0; i < 4; ++i)
#pragma unroll
      for (int j = 0; j < 8; ++j)
        acc[i][j] = fmaf(av[i], bv[j], acc[i][j]);
  }
  // epilogue: store h2 + fused attention dots (reduce over tx within 16-lane segs)
  float asv[8], adv[8];
#pragma unroll
  for (int j = 0; j < 4; ++j){
    asv[j] = as2[tx * 4 + j];      asv[4 + j] = as2[64 + tx * 4 + j];
    adv[j] = ad2[tx * 4 + j];      adv[4 + j] = ad2[64 + tx * 4 + j];
  }
#pragma unroll
  for (int i = 0; i < 4; ++i){
    int gn = n0 + ty * 4 + i;
    float s = 0.f, d = 0.f;
#pragma unroll
    for (int j = 0; j < 8; ++j){ s = fmaf(acc[i][j], asv[j], s); d = fmaf(acc[i][j], adv[j], d); }
#pragma unroll
    for (int off = 1; off < 16; off <<= 1){
      s += __shfl_xor(s, off, 16);
      d += __shfl_xor(d, off, 16);
    }
    if (gn < NN){
      float4 o0 = make_float4(acc[i][0], acc[i][1], acc[i][2], acc[i][3]);
      float4 o1v = make_float4(acc[i][4], acc[i][5], acc[i][6], acc[i][7]);
      *(float4*)(h2 + (size_t)gn * 128 + tx * 4) = o0;
      *(float4*)(h2 + (size_t)gn * 128 + tx * 4 + 64) = o1v;
      if (tx == 0){ es2[gn] = s; ed2[gn] = d; }
    }
  }
}

// ---- GAT2 aggregate: 2 nodes/wave, 32 lanes x float4, unroll-2, fused +b2 + log_softmax ----
__global__ __launch_bounds__(256) void k_gat2_agg(
    const int* __restrict__ csr, const int* __restrict__ row_start,
    const float* __restrict__ es2, const float* __restrict__ ed2,
    const float* __restrict__ h2, const float* __restrict__ b2,
    float* __restrict__ o2)
{
  int wid = (blockIdx.x * 256 + threadIdx.x) >> 6;
  int lane = threadIdx.x & 63;
  int half = lane >> 5, l32 = lane & 31;
  int d = wid * 2 + half;
  if (d >= NN) return;
  int beg = row_start[d], end = row_start[d + 1];
  float edv = ed2[d];
  float m = -INFINITY, sum = 0.f;
  float ax = 0.f, ay = 0.f, az = 0.f, aw = 0.f;
  int i = beg;
  for (; i + 1 < end; i += 2){
    int s0 = csr[i], s1 = csr[i + 1];
    float e0 = lrelu(es2[s0] + edv);
    float e1 = lrelu(es2[s1] + edv);
    float4 v0 = *(const float4*)(h2 + (size_t)s0 * 128 + l32 * 4);
    float4 v1 = *(const float4*)(h2 + (size_t)s1 * 128 + l32 * 4);
    float mn = fmaxf(m, fmaxf(e0, e1));
    float sc = __expf(m - mn), w0 = __expf(e0 - mn), w1 = __expf(e1 - mn);
    sum = sum * sc + w0 + w1;
    ax = ax * sc + v0.x * w0 + v1.x * w1;
    ay = ay * sc + v0.y * w0 + v1.y * w1;
    az = az * sc + v0.z * w0 + v1.z * w1;
    aw = aw * sc + v0.w * w0 + v1.w * w1;
    m = mn;
  }
  if (i < end){
    int s0 = csr[i];
    float e0 = lrelu(es2[s0] + edv);
    float4 v0 = *(const float4*)(h2 + (size_t)s0 * 128 + l32 * 4);
    float mn = fmaxf(m, e0);
    float sc = __expf(m - mn), w0 = __expf(e0 - mn);
    sum = sum * sc + w0;
    ax = ax * sc + v0.x * w0;
    ay = ay * sc + v0.y * w0;
    az = az * sc + v0.z * w0;
    aw = aw * sc + v0.w * w0;
  }
  float inv = 1.f / sum;
  float4 vb = *(const float4*)(b2 + l32 * 4);
  float v0 = ax * inv + vb.x, v1 = ay * inv + vb.y;
  float v2 = az * inv + vb.z, v3 = aw * inv + vb.w;
  float mx = fmaxf(fmaxf(v0, v1), fmaxf(v2, v3));
#pragma unroll
  for (int off = 16; off; off >>= 1) mx = fmaxf(mx, __shfl_xor(mx, off, 32));
  float es = __expf(v0 - mx) + __expf(v1 - mx) + __expf(v2 - mx) + __expf(v3 - mx);
#pragma unroll
  for (int off = 16; off; off >>= 1) es += __shfl_xor(es, off, 32);
  float lse = mx + __logf(es);
  float4 ov = make_float4(v0 - lse, v1 - lse, v2 - lse, v3 - lse);
  *(float4*)(o2 + (size_t)d * 128 + l32 * 4) = ov;
}

// ---- GCN aggregate: 2 nodes/wave, float4, hg pre-scaled by dinv[src] ----
__global__ __launch_bounds__(256) void k_gcn_agg(
    const int* __restrict__ csr, const int* __restrict__ row_start,
    const float* __restrict__ dinv, const float* __restrict__ hg,
    float* __restrict__ og)
{
  int wid = (blockIdx.x * 256 + threadIdx.x) >> 6;
  int lane = threadIdx.x & 63;
  int half = lane >> 5, l32 = lane & 31;
  int d = wid * 2 + half;
  if (d >= NN) return;
  int beg = row_start[d], end = row_start[d + 1];
  float ax = 0.f, ay = 0.f, az = 0.f, aw = 0.f;
  float bx = 0.f, by = 0.f, bz = 0.f, bw = 0.f;
  int i = beg;
  for (; i + 1 < end; i += 2){
    int s0 = csr[i], s1 = csr[i + 1];
    float4 v0 = *(const float4*)(hg + (size_t)s0 * 128 + l32 * 4);
    float4 v1 = *(const float4*)(hg + (size_t)s1 * 128 + l32 * 4);
    ax += v0.x; ay += v0.y; az += v0.z; aw += v0.w;
    bx += v1.x; by += v1.y; bz += v1.z; bw += v1.w;
  }
  if (i < end){
    int s0 = csr[i];
    float4 v0 = *(const float4*)(hg + (size_t)s0 * 128 + l32 * 4);
    ax += v0.x; ay += v0.y; az += v0.z; aw += v0.w;
  }
  float dd = dinv[d];
  float4 ov = make_float4((ax + bx) * dd, (ay + by) * dd, (az + bz) * dd, (aw + bw) * dd);
  *(float4*)(og + (size_t)d * 128 + l32 * 4) = ov;
}

// ---- 128x128 per-node GEMM, fp32 tiled; PRE: relu(in+bpre); POST: +bpost; SCALE: *dinv[row] ----
template<int PRE, int POST, int SCALE>
__global__ __launch_bounds__(256) void k_gemm128(const float* __restrict__ in,
    const float* __restrict__ W, const float* __restrict__ bpre,
    const float* __restrict__ bpost, const float* __restrict__ dinv,
    float* __restrict__ out)
{
  __shared__ float At[32][68];
  __shared__ float Ws[32][128];
  int t = threadIdx.x, tx = t & 15, ty = t >> 4;
  int n0 = blockIdx.x * 64;
  float acc[4][8] = {};
  for (int kt = 0; kt < 128; kt += 32){
    __syncthreads();
#pragma unroll
    for (int p = 0; p < 2; ++p){
      int f = t + p * 256;            // 512 float4 = 64 rows x 8
      int node = f >> 3, kq = f & 7;
      float4 v = make_float4(0.f, 0.f, 0.f, 0.f);
      if (n0 + node < NN){
        v = *(const float4*)(in + (size_t)(n0 + node) * 128 + kt + kq * 4);
        if (PRE){
          const float* bp = bpre + kt + kq * 4;
          v.x = fmaxf(v.x + bp[0], 0.f); v.y = fmaxf(v.y + bp[1], 0.f);
          v.z = fmaxf(v.z + bp[2], 0.f); v.w = fmaxf(v.w + bp[3], 0.f);
        }
      }
      At[kq * 4 + 0][node] = v.x; At[kq * 4 + 1][node] = v.y;
      At[kq * 4 + 2][node] = v.z; At[kq * 4 + 3][node] = v.w;
    }
#pragma unroll
    for (int p = 0; p < 4; ++p){
      int f = t + p * 256;            // 1024 float4 = 32 rows x 32
      int k = f >> 5, cq = f & 31;
      *(float4*)&Ws[k][cq * 4] = *(const float4*)(W + (size_t)(kt + k) * 128 + cq * 4);
    }
    __syncthreads();
#pragma unroll 4
    for (int k = 0; k < 32; ++k){
      float4 a  = *(const float4*)&At[k][ty * 4];
      float4 c0 = *(const float4*)&Ws[k][tx * 4];
      float4 c1 = *(const float4*)&Ws[k][tx * 4 + 64];
      float av[4] = {a.x, a.y, a.z, a.w};
      float bv[8] = {c0.x, c0.y, c0.z, c0.w, c1.x, c1.y, c1.z, c1.w};
#pragma unroll
      for (int i = 0; i < 4; ++i)
#pragma unroll
        for (int j = 0; j < 8; ++j)
          acc[i][j] = fmaf(av[i], bv[j], acc[i][j]);
    }
  }
#pragma unroll
  for (int i = 0; i < 4; ++i){
    int gn = n0 + ty * 4 + i;
    if (gn < NN){
      float sc = SCALE ? dinv[gn] : 1.f;
      float4 o0, o1v;
      o0.x  = (acc[i][0] + (POST ? bpost[tx * 4 + 0] : 0.f)) * sc;
      o0.y  = (acc[i][1] + (POST ? bpost[tx * 4 + 1] : 0.f)) * sc;
      o0.z  = (acc[i][2] + (POST ? bpost[tx * 4 + 2] : 0.f)) * sc;
      o0.w  = (acc[i][3] + (POST ? bpost[tx * 4 + 3] : 0.f)) * sc;
      o1v.x = (acc[i][4] + (POST ? bpost[64 + tx * 4 + 0] : 0.f)) * sc;
      o1v.y = (acc[i][5] + (POST ? bpost[64 + tx * 4 + 1] : 0.f)) * sc;
      o1v.z = (acc[i][6] + (POST ? bpost[64 + tx * 4 + 2] : 0.f)) * sc;
      o1v.w = (acc[i][7] + (POST ? bpost[64 + tx * 4 + 3] : 0.f)) * sc;
      *(float4*)(out + (size_t)gn * 128 + tx * 4) = o0;
      *(float4*)(out + (size_t)gn * 128 + tx * 4 + 64) = o1v;
    }
  }
}

extern "C" void kernel_launch(void* const* d_in, const int* in_sizes, int n_in,
                              void* d_out, int out_size, void* d_ws, size_t ws_size,
                              hipStream_t stream)
{
  const float* x   = (const float*)d_in[0];
  const int*   ei  = (const int*)d_in[1];
  const float* W1  = (const float*)d_in[2];
  const float* as1 = (const float*)d_in[3];
  const float* ad1 = (const float*)d_in[4];
  const float* b1  = (const float*)d_in[5];
  const float* W2  = (const float*)d_in[6];
  const float* as2 = (const float*)d_in[7];
  const float* ad2 = (const float*)d_in[8];
  const float* b2  = (const float*)d_in[9];
  const float* Wg  = (const float*)d_in[10];
  const float* bg  = (const float*)d_in[11];
  const float* Wl  = (const float*)d_in[12];
  const float* bl  = (const float*)d_in[13];
  float* out = (float*)d_out;

  float* ws = (float*)d_ws;
  const size_t n = NN;
  float* h1   = ws;                 // 48N
  float* h2   = ws + 48 * n;        // 128N (reused as hg)
  float* o1   = ws + 176 * n;       // 48N
  float* o2   = ws + 224 * n;       // 128N (lsm out; later reused as og)
  float* es1  = ws + 352 * n;       // 3N
  float* ed1  = ws + 355 * n;       // 3N
  float* es2  = ws + 358 * n;       // N
  float* ed2  = ws + 359 * n;       // N
  float* dinv = ws + 360 * n;       // N
  int* ints   = (int*)(ws + 361 * n);
  int* deg_i     = ints;            // N   (zeroed)
  int* cur       = ints + n;        // N   (zeroed)
  int* row_start = ints + 2 * n;    // N+1
  int* csr       = ints + 3 * n + 1;// ET
  float* og = o2;                   // overwrite o2 after gemm128<Wg> consumed it

  hipMemsetAsync(deg_i, 0, 2 * n * sizeof(int), stream);

  const int egrid = (ET + 255) / 256;
  const int wgrid = (NN * 64) / 256;        // one wave per node
  const int hgrid = (NN / 2 * 64) / 256;    // two nodes per wave
  k_hist<<<egrid, 256, 0, stream>>>(ei, deg_i);
  k_scan<<<1, 1024, 0, stream>>>(deg_i, row_start, dinv);
  k_fill<<<egrid, 256, 0, stream>>>(ei, row_start, cur, csr);
  k_gat1_gemm<<<(NN + 127) / 128, 256, 0, stream>>>(x, W1, h1);
  k_att1<<<wgrid, 256, 0, stream>>>(h1, as1, ad1, es1, ed1);
  k_gat1_agg<<<wgrid, 256, 0, stream>>>(csr, row_start, es1, ed1, h1, b1, o1);
  k_gat2_gemm<<<(NN + 63) / 64, 256, 0, stream>>>(o1, W2, as2, ad2, h2, es2, ed2);
  k_gat2_agg<<<hgrid, 256, 0, stream>>>(csr, row_start, es2, ed2, h2, b2, o2);
  k_gemm128<0, 0, 1><<<(NN + 63) / 64, 256, 0, stream>>>(o2, Wg, nullptr, nullptr, dinv, h2);
  k_gcn_agg<<<hgrid, 256, 0, stream>>>(csr, row_start, dinv, h2, og);
  k_gemm128<1, 1, 0><<<(NN + 63) / 64, 256, 0, stream>>>(og, Wl, bg, bl, nullptr, out);
}

// Round 4
// 565.163 us; speedup vs baseline: 3.1780x; 1.2096x over previous
//
#include <hip/hip_runtime.h>
#include <hip/hip_bf16.h>
#include <math.h>

#define NN 50000
#define EE 800000
#define ET 850000
#define NB 196          // ceil(NN/256)
#define NEG 0.2f

static __device__ __forceinline__ float lrelu(float x){ return x > 0.f ? x : NEG * x; }
static __device__ __forceinline__ void edge_sd(const int* __restrict__ ei, int e, int& s, int& d){
  if (e < EE){ s = ei[e]; d = ei[e + EE]; } else { s = e - EE; d = s; }
}

// ---- CSR build ----
__global__ __launch_bounds__(256) void k_hist(const int* __restrict__ ei, int* __restrict__ deg_i)
{
  int e = blockIdx.x * 256 + threadIdx.x;
  if (e >= ET) return;
  int s, d; edge_sd(ei, e, s, d);
  atomicAdd(deg_i + d, 1);
}

// multi-block scan, phase 1: per-block sums
__global__ __launch_bounds__(256) void k_scan_part(const int* __restrict__ deg_i, int* __restrict__ bsum)
{
  __shared__ int wsum[4];
  int t = threadIdx.x;
  int i = blockIdx.x * 256 + t;
  int v = (i < NN) ? deg_i[i] : 0;
  int r = v;
#pragma unroll
  for (int off = 32; off; off >>= 1) r += __shfl_xor(r, off);
  if ((t & 63) == 0) wsum[t >> 6] = r;
  __syncthreads();
  if (t == 0) bsum[blockIdx.x] = wsum[0] + wsum[1] + wsum[2] + wsum[3];
}

// phase 2: exclusive scan of NB block sums (single tiny block)
__global__ __launch_bounds__(256) void k_scan_top(const int* __restrict__ bsum, int* __restrict__ boff)
{
  __shared__ int bs[256];
  int t = threadIdx.x;
  int v = (t < NB) ? bsum[t] : 0;
  bs[t] = v;
  __syncthreads();
  for (int off = 1; off < 256; off <<= 1){
    int add = (t >= off) ? bs[t - off] : 0;
    __syncthreads();
    bs[t] += add;
    __syncthreads();
  }
  if (t < NB) boff[t] = bs[t] - v;
}

// phase 3: per-block local exclusive scan + block offset; fused dinv
__global__ __launch_bounds__(256) void k_scan_fin(const int* __restrict__ deg_i,
    const int* __restrict__ boff, int* __restrict__ row_start, float* __restrict__ dinv)
{
  __shared__ int bs[256];
  int t = threadIdx.x;
  int i = blockIdx.x * 256 + t;
  int v = (i < NN) ? deg_i[i] : 0;
  bs[t] = v;
  __syncthreads();
  for (int off = 1; off < 256; off <<= 1){
    int add = (t >= off) ? bs[t - off] : 0;
    __syncthreads();
    bs[t] += add;
    __syncthreads();
  }
  if (i < NN){
    row_start[i] = boff[blockIdx.x] + bs[t] - v;
    dinv[i] = rsqrtf(fmaxf((float)v, 1.0f));
  }
  if (i == 0) row_start[NN] = ET;
}

__global__ __launch_bounds__(256) void k_fill(const int* __restrict__ ei,
    const int* __restrict__ row_start, int* __restrict__ cur, int* __restrict__ csr)
{
  int e = blockIdx.x * 256 + threadIdx.x;
  if (e >= ET) return;
  int s, d; edge_sd(ei, e, s, d);
  int pos = atomicAdd(cur + d, 1);
  csr[row_start[d] + pos] = s;
}

// ---- GAT1 GEMM: h1[50000x48] = x[50000x512] @ W1[512x48], fused es1/ed1 epilogue ----
// block: 128 nodes x 48 outs, K-tile 64, micro 8m x 3n, 256 thr
__global__ __launch_bounds__(256) void k_gat1_gemm(
    const float* __restrict__ x, const float* __restrict__ W1,
    const float* __restrict__ as1, const float* __restrict__ ad1,
    float* __restrict__ h1, float* __restrict__ es1, float* __restrict__ ed1)
{
  __shared__ float At[64][132];   // [k][node]
  __shared__ float Bs[64][52];    // [k][out]
  int t = threadIdx.x;
  int tx = t & 15, ty = t >> 4;
  int n0 = blockIdx.x * 128;
  float acc[8][3] = {};
  for (int kt = 0; kt < 512; kt += 64){
    __syncthreads();
#pragma unroll
    for (int p = 0; p < 8; ++p){
      int f = t + p * 256;
      int node = f >> 4, kq = f & 15;
      float4 v = make_float4(0.f, 0.f, 0.f, 0.f);
      int gn = n0 + node;
      if (gn < NN) v = *(const float4*)(x + (size_t)gn * 512 + kt + kq * 4);
      At[kq * 4 + 0][node] = v.x; At[kq * 4 + 1][node] = v.y;
      At[kq * 4 + 2][node] = v.z; At[kq * 4 + 3][node] = v.w;
    }
#pragma unroll
    for (int p = 0; p < 3; ++p){
      int f = t + p * 256;
      int k = f / 12, oq = f % 12;
      *(float4*)&Bs[k][oq * 4] = *(const float4*)(W1 + (size_t)(kt + k) * 48 + oq * 4);
    }
    __syncthreads();
#pragma unroll 4
    for (int k = 0; k < 64; ++k){
      float4 a0 = *(const float4*)&At[k][ty * 8];
      float4 a1 = *(const float4*)&At[k][ty * 8 + 4];
      float b0 = Bs[k][tx * 3 + 0], b1 = Bs[k][tx * 3 + 1], b2 = Bs[k][tx * 3 + 2];
      float av[8] = {a0.x, a0.y, a0.z, a0.w, a1.x, a1.y, a1.z, a1.w};
#pragma unroll
      for (int i = 0; i < 8; ++i){
        acc[i][0] = fmaf(av[i], b0, acc[i][0]);
        acc[i][1] = fmaf(av[i], b1, acc[i][1]);
        acc[i][2] = fmaf(av[i], b2, acc[i][2]);
      }
    }
  }
#pragma unroll
  for (int i = 0; i < 8; ++i){
    int gn = n0 + ty * 8 + i;
    // fused attention partial dots: o = tx*3+j, head = o>>4
    float ps0 = 0.f, ps1 = 0.f, ps2 = 0.f, pd0 = 0.f, pd1 = 0.f, pd2 = 0.f;
#pragma unroll
    for (int j = 0; j < 3; ++j){
      int o = tx * 3 + j;
      int h = o >> 4;
      float a = acc[i][j];
      float vs = a * as1[o], vd = a * ad1[o];
      if (h == 0){ ps0 += vs; pd0 += vd; }
      else if (h == 1){ ps1 += vs; pd1 += vd; }
      else { ps2 += vs; pd2 += vd; }
    }
#pragma unroll
    for (int off = 1; off < 16; off <<= 1){
      ps0 += __shfl_xor(ps0, off, 16); ps1 += __shfl_xor(ps1, off, 16); ps2 += __shfl_xor(ps2, off, 16);
      pd0 += __shfl_xor(pd0, off, 16); pd1 += __shfl_xor(pd1, off, 16); pd2 += __shfl_xor(pd2, off, 16);
    }
    if (gn < NN){
      float* o = h1 + (size_t)gn * 48 + tx * 3;
      o[0] = acc[i][0]; o[1] = acc[i][1]; o[2] = acc[i][2];
      if (tx == 0){
        es1[(size_t)gn * 3 + 0] = ps0; es1[(size_t)gn * 3 + 1] = ps1; es1[(size_t)gn * 3 + 2] = ps2;
        ed1[(size_t)gn * 3 + 0] = pd0; ed1[(size_t)gn * 3 + 1] = pd1; ed1[(size_t)gn * 3 + 2] = pd2;
      }
    }
  }
}

// ---- GAT1 aggregate: one wave/node, online softmax, unroll-2, fused +b1 + ELU ----
__global__ __launch_bounds__(256) void k_gat1_agg(
    const int* __restrict__ csr, const int* __restrict__ row_start,
    const float* __restrict__ es1, const float* __restrict__ ed1,
    const float* __restrict__ h1, const float* __restrict__ b1,
    float* __restrict__ o1)
{
  int dn = (blockIdx.x * 256 + threadIdx.x) >> 6;
  int lane = threadIdx.x & 63;
  if (dn >= NN) return;
  bool act = lane < 48;
  int hd = act ? (lane >> 4) : 0;
  int beg = row_start[dn], end = row_start[dn + 1];
  float edv = ed1[(size_t)dn * 3 + hd];
  float m = -INFINITY, sum = 0.f, acc = 0.f;
  int i = beg;
  for (; i + 1 < end; i += 2){
    int s0 = csr[i], s1 = csr[i + 1];
    float e0 = lrelu(es1[(size_t)s0 * 3 + hd] + edv);
    float e1 = lrelu(es1[(size_t)s1 * 3 + hd] + edv);
    float h0 = act ? h1[(size_t)s0 * 48 + lane] : 0.f;
    float h1v = act ? h1[(size_t)s1 * 48 + lane] : 0.f;
    float mn = fmaxf(m, fmaxf(e0, e1));
    float sc = __expf(m - mn), w0 = __expf(e0 - mn), w1 = __expf(e1 - mn);
    sum = sum * sc + w0 + w1;
    acc = acc * sc + h0 * w0 + h1v * w1;
    m = mn;
  }
  if (i < end){
    int s0 = csr[i];
    float e0 = lrelu(es1[(size_t)s0 * 3 + hd] + edv);
    float h0 = act ? h1[(size_t)s0 * 48 + lane] : 0.f;
    float mn = fmaxf(m, e0);
    float sc = __expf(m - mn), w0 = __expf(e0 - mn);
    sum = sum * sc + w0;
    acc = acc * sc + h0 * w0;
  }
  if (act){
    float v = acc / sum + b1[lane];
    o1[(size_t)dn * 48 + lane] = v > 0.f ? v : expm1f(v);
  }
}

// ---- GAT2 GEMM: h2[50000x128] = o1[50000x48] @ W2[48x128]; fused es2/ed2 ----
__global__ __launch_bounds__(256) void k_gat2_gemm(const float* __restrict__ o1,
    const float* __restrict__ W2, const float* __restrict__ as2, const float* __restrict__ ad2,
    float* __restrict__ h2, float* __restrict__ es2, float* __restrict__ ed2)
{
  __shared__ float At[48][68];
  __shared__ float Ws[48][128];
  int t = threadIdx.x, tx = t & 15, ty = t >> 4;
  int n0 = blockIdx.x * 64;
#pragma unroll
  for (int p = 0; p < 3; ++p){
    int f = t + p * 256;           // 768 float4 = 64 rows x 12
    int node = f / 12, kq = f % 12;
    float4 v = make_float4(0.f, 0.f, 0.f, 0.f);
    if (n0 + node < NN) v = *(const float4*)(o1 + (size_t)(n0 + node) * 48 + kq * 4);
    At[kq * 4 + 0][node] = v.x; At[kq * 4 + 1][node] = v.y;
    At[kq * 4 + 2][node] = v.z; At[kq * 4 + 3][node] = v.w;
  }
#pragma unroll
  for (int p = 0; p < 6; ++p){
    int f = t + p * 256;           // 1536 float4 = 48 rows x 32
    int k = f >> 5, cq = f & 31;
    *(float4*)&Ws[k][cq * 4] = *(const float4*)(W2 + (size_t)k * 128 + cq * 4);
  }
  __syncthreads();
  float acc[4][8] = {};
#pragma unroll 4
  for (int k = 0; k < 48; ++k){
    float4 a  = *(const float4*)&At[k][ty * 4];
    float4 c0 = *(const float4*)&Ws[k][tx * 4];
    float4 c1 = *(const float4*)&Ws[k][tx * 4 + 64];
    float av[4] = {a.x, a.y, a.z, a.w};
    float bv[8] = {c0.x, c0.y, c0.z, c0.w, c1.x, c1.y, c1.z, c1.w};
#pragma unroll
    for (int i = 0; i < 4; ++i)
#pragma unroll
      for (int j = 0; j < 8; ++j)
        acc[i][j] = fmaf(av[i], bv[j], acc[i][j]);
  }
  float asv[8], adv[8];
#pragma unroll
  for (int j = 0; j < 4; ++j){
    asv[j] = as2[tx * 4 + j];      asv[4 + j] = as2[64 + tx * 4 + j];
    adv[j] = ad2[tx * 4 + j];      adv[4 + j] = ad2[64 + tx * 4 + j];
  }
#pragma unroll
  for (int i = 0; i < 4; ++i){
    int gn = n0 + ty * 4 + i;
    float s = 0.f, d = 0.f;
#pragma unroll
    for (int j = 0; j < 8; ++j){ s = fmaf(acc[i][j], asv[j], s); d = fmaf(acc[i][j], adv[j], d); }
#pragma unroll
    for (int off = 1; off < 16; off <<= 1){
      s += __shfl_xor(s, off, 16);
      d += __shfl_xor(d, off, 16);
    }
    if (gn < NN){
      float4 o0 = make_float4(acc[i][0], acc[i][1], acc[i][2], acc[i][3]);
      float4 o1v = make_float4(acc[i][4], acc[i][5], acc[i][6], acc[i][7]);
      *(float4*)(h2 + (size_t)gn * 128 + tx * 4) = o0;
      *(float4*)(h2 + (size_t)gn * 128 + tx * 4 + 64) = o1v;
      if (tx == 0){ es2[gn] = s; ed2[gn] = d; }
    }
  }
}

// ---- GAT2 aggregate: 2 nodes/wave, 32 lanes x float4, unroll-2, fused +b2 + log_softmax ----
__global__ __launch_bounds__(256) void k_gat2_agg(
    const int* __restrict__ csr, const int* __restrict__ row_start,
    const float* __restrict__ es2, const float* __restrict__ ed2,
    const float* __restrict__ h2, const float* __restrict__ b2,
    float* __restrict__ o2)
{
  int wid = (blockIdx.x * 256 + threadIdx.x) >> 6;
  int lane = threadIdx.x & 63;
  int half = lane >> 5, l32 = lane & 31;
  int d = wid * 2 + half;
  if (d >= NN) return;
  int beg = row_start[d], end = row_start[d + 1];
  float edv = ed2[d];
  float m = -INFINITY, sum = 0.f;
  float ax = 0.f, ay = 0.f, az = 0.f, aw = 0.f;
  int i = beg;
  for (; i + 1 < end; i += 2){
    int s0 = csr[i], s1 = csr[i + 1];
    float e0 = lrelu(es2[s0] + edv);
    float e1 = lrelu(es2[s1] + edv);
    float4 v0 = *(const float4*)(h2 + (size_t)s0 * 128 + l32 * 4);
    float4 v1 = *(const float4*)(h2 + (size_t)s1 * 128 + l32 * 4);
    float mn = fmaxf(m, fmaxf(e0, e1));
    float sc = __expf(m - mn), w0 = __expf(e0 - mn), w1 = __expf(e1 - mn);
    sum = sum * sc + w0 + w1;
    ax = ax * sc + v0.x * w0 + v1.x * w1;
    ay = ay * sc + v0.y * w0 + v1.y * w1;
    az = az * sc + v0.z * w0 + v1.z * w1;
    aw = aw * sc + v0.w * w0 + v1.w * w1;
    m = mn;
  }
  if (i < end){
    int s0 = csr[i];
    float e0 = lrelu(es2[s0] + edv);
    float4 v0 = *(const float4*)(h2 + (size_t)s0 * 128 + l32 * 4);
    float mn = fmaxf(m, e0);
    float sc = __expf(m - mn), w0 = __expf(e0 - mn);
    sum = sum * sc + w0;
    ax = ax * sc + v0.x * w0;
    ay = ay * sc + v0.y * w0;
    az = az * sc + v0.z * w0;
    aw = aw * sc + v0.w * w0;
  }
  float inv = 1.f / sum;
  float4 vb = *(const float4*)(b2 + l32 * 4);
  float v0 = ax * inv + vb.x, v1 = ay * inv + vb.y;
  float v2 = az * inv + vb.z, v3 = aw * inv + vb.w;
  float mx = fmaxf(fmaxf(v0, v1), fmaxf(v2, v3));
#pragma unroll
  for (int off = 16; off; off >>= 1) mx = fmaxf(mx, __shfl_xor(mx, off, 32));
  float es = __expf(v0 - mx) + __expf(v1 - mx) + __expf(v2 - mx) + __expf(v3 - mx);
#pragma unroll
  for (int off = 16; off; off >>= 1) es += __shfl_xor(es, off, 32);
  float lse = mx + __logf(es);
  float4 ov = make_float4(v0 - lse, v1 - lse, v2 - lse, v3 - lse);
  *(float4*)(o2 + (size_t)d * 128 + l32 * 4) = ov;
}

// ---- GCN aggregate: 2 nodes/wave, float4, hg pre-scaled by dinv[src] ----
__global__ __launch_bounds__(256) void k_gcn_agg(
    const int* __restrict__ csr, const int* __restrict__ row_start,
    const float* __restrict__ dinv, const float* __restrict__ hg,
    float* __restrict__ og)
{
  int wid = (blockIdx.x * 256 + threadIdx.x) >> 6;
  int lane = threadIdx.x & 63;
  int half = lane >> 5, l32 = lane & 31;
  int d = wid * 2 + half;
  if (d >= NN) return;
  int beg = row_start[d], end = row_start[d + 1];
  float ax = 0.f, ay = 0.f, az = 0.f, aw = 0.f;
  float bx = 0.f, by = 0.f, bz = 0.f, bw = 0.f;
  int i = beg;
  for (; i + 1 < end; i += 2){
    int s0 = csr[i], s1 = csr[i + 1];
    float4 v0 = *(const float4*)(hg + (size_t)s0 * 128 + l32 * 4);
    float4 v1 = *(const float4*)(hg + (size_t)s1 * 128 + l32 * 4);
    ax += v0.x; ay += v0.y; az += v0.z; aw += v0.w;
    bx += v1.x; by += v1.y; bz += v1.z; bw += v1.w;
  }
  if (i < end){
    int s0 = csr[i];
    float4 v0 = *(const float4*)(hg + (size_t)s0 * 128 + l32 * 4);
    ax += v0.x; ay += v0.y; az += v0.z; aw += v0.w;
  }
  float dd = dinv[d];
  float4 ov = make_float4((ax + bx) * dd, (ay + by) * dd, (az + bz) * dd, (aw + bw) * dd);
  *(float4*)(og + (size_t)d * 128 + l32 * 4) = ov;
}

// ---- 128x128 per-node GEMM, fp32 tiled; PRE: relu(in+bpre); POST: +bpost; SCALE: *dinv[row] ----
template<int PRE, int POST, int SCALE>
__global__ __launch_bounds__(256) void k_gemm128(const float* __restrict__ in,
    const float* __restrict__ W, const float* __restrict__ bpre,
    const float* __restrict__ bpost, const float* __restrict__ dinv,
    float* __restrict__ out)
{
  __shared__ float At[32][68];
  __shared__ float Ws[32][128];
  int t = threadIdx.x, tx = t & 15, ty = t >> 4;
  int n0 = blockIdx.x * 64;
  float acc[4][8] = {};
  for (int kt = 0; kt < 128; kt += 32){
    __syncthreads();
#pragma unroll
    for (int p = 0; p < 2; ++p){
      int f = t + p * 256;            // 512 float4 = 64 rows x 8
      int node = f >> 3, kq = f & 7;
      float4 v = make_float4(0.f, 0.f, 0.f, 0.f);
      if (n0 + node < NN){
        v = *(const float4*)(in + (size_t)(n0 + node) * 128 + kt + kq * 4);
        if (PRE){
          const float* bp = bpre + kt + kq * 4;
          v.x = fmaxf(v.x + bp[0], 0.f); v.y = fmaxf(v.y + bp[1], 0.f);
          v.z = fmaxf(v.z + bp[2], 0.f); v.w = fmaxf(v.w + bp[3], 0.f);
        }
      }
      At[kq * 4 + 0][node] = v.x; At[kq * 4 + 1][node] = v.y;
      At[kq * 4 + 2][node] = v.z; At[kq * 4 + 3][node] = v.w;
    }
#pragma unroll
    for (int p = 0; p < 4; ++p){
      int f = t + p * 256;            // 1024 float4 = 32 rows x 32
      int k = f >> 5, cq = f & 31;
      *(float4*)&Ws[k][cq * 4] = *(const float4*)(W + (size_t)(kt + k) * 128 + cq * 4);
    }
    __syncthreads();
#pragma unroll 4
    for (int k = 0; k < 32; ++k){
      float4 a  = *(const float4*)&At[k][ty * 4];
      float4 c0 = *(const float4*)&Ws[k][tx * 4];
      float4 c1 = *(const float4*)&Ws[k][tx * 4 + 64];
      float av[4] = {a.x, a.y, a.z, a.w};
      float bv[8] = {c0.x, c0.y, c0.z, c0.w, c1.x, c1.y, c1.z, c1.w};
#pragma unroll
      for (int i = 0; i < 4; ++i)
#pragma unroll
        for (int j = 0; j < 8; ++j)
          acc[i][j] = fmaf(av[i], bv[j], acc[i][j]);
    }
  }
#pragma unroll
  for (int i = 0; i < 4; ++i){
    int gn = n0 + ty * 4 + i;
    if (gn < NN){
      float sc = SCALE ? dinv[gn] : 1.f;
      float4 o0, o1v;
      o0.x  = (acc[i][0] + (POST ? bpost[tx * 4 + 0] : 0.f)) * sc;
      o0.y  = (acc[i][1] + (POST ? bpost[tx * 4 + 1] : 0.f)) * sc;
      o0.z  = (acc[i][2] + (POST ? bpost[tx * 4 + 2] : 0.f)) * sc;
      o0.w  = (acc[i][3] + (POST ? bpost[tx * 4 + 3] : 0.f)) * sc;
      o1v.x = (acc[i][4] + (POST ? bpost[64 + tx * 4 + 0] : 0.f)) * sc;
      o1v.y = (acc[i][5] + (POST ? bpost[64 + tx * 4 + 1] : 0.f)) * sc;
      o1v.z = (acc[i][6] + (POST ? bpost[64 + tx * 4 + 2] : 0.f)) * sc;
      o1v.w = (acc[i][7] + (POST ? bpost[64 + tx * 4 + 3] : 0.f)) * sc;
      *(float4*)(out + (size_t)gn * 128 + tx * 4) = o0;
      *(float4*)(out + (size_t)gn * 128 + tx * 4 + 64) = o1v;
    }
  }
}

extern "C" void kernel_launch(void* const* d_in, const int* in_sizes, int n_in,
                              void* d_out, int out_size, void* d_ws, size_t ws_size,
                              hipStream_t stream)
{
  const float* x   = (const float*)d_in[0];
  const int*   ei  = (const int*)d_in[1];
  const float* W1  = (const float*)d_in[2];
  const float* as1 = (const float*)d_in[3];
  const float* ad1 = (const float*)d_in[4];
  const float* b1  = (const float*)d_in[5];
  const float* W2  = (const float*)d_in[6];
  const float* as2 = (const float*)d_in[7];
  const float* ad2 = (const float*)d_in[8];
  const float* b2  = (const float*)d_in[9];
  const float* Wg  = (const float*)d_in[10];
  const float* bg  = (const float*)d_in[11];
  const float* Wl  = (const float*)d_in[12];
  const float* bl  = (const float*)d_in[13];
  float* out = (float*)d_out;

  float* ws = (float*)d_ws;
  const size_t n = NN;
  float* h1   = ws;                 // 48N
  float* h2   = ws + 48 * n;        // 128N (reused as hg)
  float* o1   = ws + 176 * n;       // 48N
  float* o2   = ws + 224 * n;       // 128N (lsm out; later reused as og)
  float* es1  = ws + 352 * n;       // 3N
  float* ed1  = ws + 355 * n;       // 3N
  float* es2  = ws + 358 * n;       // N
  float* ed2  = ws + 359 * n;       // N
  float* dinv = ws + 360 * n;       // N
  int* ints   = (int*)(ws + 361 * n);
  int* deg_i     = ints;            // N   (zeroed)
  int* cur       = ints + n;        // N   (zeroed)
  int* row_start = ints + 2 * n;    // N+1
  int* csr       = ints + 3 * n + 1;// ET
  int* bsum      = ints + 3 * n + 1 + ET;      // NB
  int* boff      = ints + 3 * n + 1 + ET + NB; // NB
  float* og = o2;                   // overwrite o2 after gemm128<Wg> consumed it

  hipMemsetAsync(deg_i, 0, 2 * n * sizeof(int), stream);

  const int egrid = (ET + 255) / 256;
  const int wgrid = (NN * 64) / 256;        // one wave per node
  const int hgrid = (NN / 2 * 64) / 256;    // two nodes per wave
  k_hist<<<egrid, 256, 0, stream>>>(ei, deg_i);
  k_scan_part<<<NB, 256, 0, stream>>>(deg_i, bsum);
  k_scan_top<<<1, 256, 0, stream>>>(bsum, boff);
  k_scan_fin<<<NB, 256, 0, stream>>>(deg_i, boff, row_start, dinv);
  k_fill<<<egrid, 256, 0, stream>>>(ei, row_start, cur, csr);
  k_gat1_gemm<<<(NN + 127) / 128, 256, 0, stream>>>(x, W1, as1, ad1, h1, es1, ed1);
  k_gat1_agg<<<wgrid, 256, 0, stream>>>(csr, row_start, es1, ed1, h1, b1, o1);
  k_gat2_gemm<<<(NN + 63) / 64, 256, 0, stream>>>(o1, W2, as2, ad2, h2, es2, ed2);
  k_gat2_agg<<<hgrid, 256, 0, stream>>>(csr, row_start, es2, ed2, h2, b2, o2);
  k_gemm128<0, 0, 1><<<(NN + 63) / 64, 256, 0, stream>>>(o2, Wg, nullptr, nullptr, dinv, h2);
  k_gcn_agg<<<hgrid, 256, 0, stream>>>(csr, row_start, dinv, h2, og);
  k_gemm128<1, 1, 0><<<(NN + 63) / 64, 256, 0, stream>>>(og, Wl, bg, bl, nullptr, out);
}

// Round 5
// 552.055 us; speedup vs baseline: 3.2535x; 1.0237x over previous
//
#include <hip/hip_runtime.h>
#include <hip/hip_bf16.h>
#include <math.h>

#define NN 50000
#define EE 800000
#define ET 850000
#define NB 196          // ceil(NN/256)
#define NEG 0.2f

static __device__ __forceinline__ float lrelu(float x){ return x > 0.f ? x : NEG * x; }
static __device__ __forceinline__ void edge_sd(const int* __restrict__ ei, int e, int& s, int& d){
  if (e < EE){ s = ei[e]; d = ei[e + EE]; } else { s = e - EE; d = s; }
}

// ---- CSR build ----
__global__ __launch_bounds__(256) void k_hist(const int* __restrict__ ei, int* __restrict__ deg_i)
{
  int e = blockIdx.x * 256 + threadIdx.x;
  if (e >= ET) return;
  int s, d; edge_sd(ei, e, s, d);
  atomicAdd(deg_i + d, 1);
}

__global__ __launch_bounds__(256) void k_scan_part(const int* __restrict__ deg_i, int* __restrict__ bsum)
{
  __shared__ int wsum[4];
  int t = threadIdx.x;
  int i = blockIdx.x * 256 + t;
  int v = (i < NN) ? deg_i[i] : 0;
  int r = v;
#pragma unroll
  for (int off = 32; off; off >>= 1) r += __shfl_xor(r, off);
  if ((t & 63) == 0) wsum[t >> 6] = r;
  __syncthreads();
  if (t == 0) bsum[blockIdx.x] = wsum[0] + wsum[1] + wsum[2] + wsum[3];
}

__global__ __launch_bounds__(256) void k_scan_top(const int* __restrict__ bsum, int* __restrict__ boff)
{
  __shared__ int bs[256];
  int t = threadIdx.x;
  int v = (t < NB) ? bsum[t] : 0;
  bs[t] = v;
  __syncthreads();
  for (int off = 1; off < 256; off <<= 1){
    int add = (t >= off) ? bs[t - off] : 0;
    __syncthreads();
    bs[t] += add;
    __syncthreads();
  }
  if (t < NB) boff[t] = bs[t] - v;
}

__global__ __launch_bounds__(256) void k_scan_fin(const int* __restrict__ deg_i,
    const int* __restrict__ boff, int* __restrict__ row_start, float* __restrict__ dinv)
{
  __shared__ int bs[256];
  int t = threadIdx.x;
  int i = blockIdx.x * 256 + t;
  int v = (i < NN) ? deg_i[i] : 0;
  bs[t] = v;
  __syncthreads();
  for (int off = 1; off < 256; off <<= 1){
    int add = (t >= off) ? bs[t - off] : 0;
    __syncthreads();
    bs[t] += add;
    __syncthreads();
  }
  if (i < NN){
    row_start[i] = boff[blockIdx.x] + bs[t] - v;
    dinv[i] = rsqrtf(fmaxf((float)v, 1.0f));
  }
  if (i == 0) row_start[NN] = ET;
}

__global__ __launch_bounds__(256) void k_fill(const int* __restrict__ ei,
    const int* __restrict__ row_start, int* __restrict__ cur, int* __restrict__ csr)
{
  int e = blockIdx.x * 256 + threadIdx.x;
  if (e >= ET) return;
  int s, d; edge_sd(ei, e, s, d);
  int pos = atomicAdd(cur + d, 1);
  csr[row_start[d] + pos] = s;
}

// ---- GAT1 GEMM: h1[50000x48] = x[50000x512] @ W1[512x48], fused es1/ed1 epilogue ----
// block: 64 nodes x 48 outs, K-tile 64, micro 4m x 3n, 256 thr (tx:16 n-groups, ty:16 m-groups)
// grid 782 = 3.05 blocks/CU (balanced); At stride 69 -> 2-way write aliasing (free)
__global__ __launch_bounds__(256) void k_gat1_gemm(
    const float* __restrict__ x, const float* __restrict__ W1,
    const float* __restrict__ as1, const float* __restrict__ ad1,
    float* __restrict__ h1, float* __restrict__ es1, float* __restrict__ ed1)
{
  __shared__ float At[64][69];   // [k][node], stride 69: 69*4 % 32 = 20 -> 2-way max
  __shared__ float Bs[64][52];   // [k][out]
  int t = threadIdx.x;
  int tx = t & 15, ty = t >> 4;
  int n0 = blockIdx.x * 64;
  float acc[4][3] = {};
  for (int kt = 0; kt < 512; kt += 64){
    __syncthreads();
    // stage x tile (64 nodes x 64 k) as float4, transposed into At
#pragma unroll
    for (int p = 0; p < 4; ++p){
      int f = t + p * 256;
      int node = f >> 4, kq = f & 15;
      float4 v = make_float4(0.f, 0.f, 0.f, 0.f);
      int gn = n0 + node;
      if (gn < NN) v = *(const float4*)(x + (size_t)gn * 512 + kt + kq * 4);
      At[kq * 4 + 0][node] = v.x; At[kq * 4 + 1][node] = v.y;
      At[kq * 4 + 2][node] = v.z; At[kq * 4 + 3][node] = v.w;
    }
    // stage W1 rows kt..kt+63 (64x48)
#pragma unroll
    for (int p = 0; p < 3; ++p){
      int f = t + p * 256;
      int k = f / 12, oq = f % 12;
      *(float4*)&Bs[k][oq * 4] = *(const float4*)(W1 + (size_t)(kt + k) * 48 + oq * 4);
    }
    __syncthreads();
#pragma unroll 8
    for (int k = 0; k < 64; ++k){
      float4 a = *(const float4*)&At[k][ty * 4];
      float b0 = Bs[k][tx * 3 + 0], b1 = Bs[k][tx * 3 + 1], b2 = Bs[k][tx * 3 + 2];
      float av[4] = {a.x, a.y, a.z, a.w};
#pragma unroll
      for (int i = 0; i < 4; ++i){
        acc[i][0] = fmaf(av[i], b0, acc[i][0]);
        acc[i][1] = fmaf(av[i], b1, acc[i][1]);
        acc[i][2] = fmaf(av[i], b2, acc[i][2]);
      }
    }
  }
#pragma unroll
  for (int i = 0; i < 4; ++i){
    int gn = n0 + ty * 4 + i;
    float ps0 = 0.f, ps1 = 0.f, ps2 = 0.f, pd0 = 0.f, pd1 = 0.f, pd2 = 0.f;
#pragma unroll
    for (int j = 0; j < 3; ++j){
      int o = tx * 3 + j;
      int h = o >> 4;
      float a = acc[i][j];
      float vs = a * as1[o], vd = a * ad1[o];
      if (h == 0){ ps0 += vs; pd0 += vd; }
      else if (h == 1){ ps1 += vs; pd1 += vd; }
      else { ps2 += vs; pd2 += vd; }
    }
#pragma unroll
    for (int off = 1; off < 16; off <<= 1){
      ps0 += __shfl_xor(ps0, off, 16); ps1 += __shfl_xor(ps1, off, 16); ps2 += __shfl_xor(ps2, off, 16);
      pd0 += __shfl_xor(pd0, off, 16); pd1 += __shfl_xor(pd1, off, 16); pd2 += __shfl_xor(pd2, off, 16);
    }
    if (gn < NN){
      float* o = h1 + (size_t)gn * 48 + tx * 3;
      o[0] = acc[i][0]; o[1] = acc[i][1]; o[2] = acc[i][2];
      if (tx == 0){
        es1[(size_t)gn * 3 + 0] = ps0; es1[(size_t)gn * 3 + 1] = ps1; es1[(size_t)gn * 3 + 2] = ps2;
        ed1[(size_t)gn * 3 + 0] = pd0; ed1[(size_t)gn * 3 + 1] = pd1; ed1[(size_t)gn * 3 + 2] = pd2;
      }
    }
  }
}

// ---- GAT1 aggregate: one wave/node, online softmax, unroll-2, fused +b1 + ELU ----
__global__ __launch_bounds__(256) void k_gat1_agg(
    const int* __restrict__ csr, const int* __restrict__ row_start,
    const float* __restrict__ es1, const float* __restrict__ ed1,
    const float* __restrict__ h1, const float* __restrict__ b1,
    float* __restrict__ o1)
{
  int dn = (blockIdx.x * 256 + threadIdx.x) >> 6;
  int lane = threadIdx.x & 63;
  if (dn >= NN) return;
  bool act = lane < 48;
  int hd = act ? (lane >> 4) : 0;
  int beg = row_start[dn], end = row_start[dn + 1];
  float edv = ed1[(size_t)dn * 3 + hd];
  float m = -INFINITY, sum = 0.f, acc = 0.f;
  int i = beg;
  for (; i + 1 < end; i += 2){
    int s0 = csr[i], s1 = csr[i + 1];
    float e0 = lrelu(es1[(size_t)s0 * 3 + hd] + edv);
    float e1 = lrelu(es1[(size_t)s1 * 3 + hd] + edv);
    float h0 = act ? h1[(size_t)s0 * 48 + lane] : 0.f;
    float h1v = act ? h1[(size_t)s1 * 48 + lane] : 0.f;
    float mn = fmaxf(m, fmaxf(e0, e1));
    float sc = __expf(m - mn), w0 = __expf(e0 - mn), w1 = __expf(e1 - mn);
    sum = sum * sc + w0 + w1;
    acc = acc * sc + h0 * w0 + h1v * w1;
    m = mn;
  }
  if (i < end){
    int s0 = csr[i];
    float e0 = lrelu(es1[(size_t)s0 * 3 + hd] + edv);
    float h0 = act ? h1[(size_t)s0 * 48 + lane] : 0.f;
    float mn = fmaxf(m, e0);
    float sc = __expf(m - mn), w0 = __expf(e0 - mn);
    sum = sum * sc + w0;
    acc = acc * sc + h0 * w0;
  }
  if (act){
    float v = acc / sum + b1[lane];
    o1[(size_t)dn * 48 + lane] = v > 0.f ? v : expm1f(v);
  }
}

// ---- GAT2 GEMM: h2[50000x128] = o1[50000x48] @ W2[48x128]; fused es2/ed2 ----
__global__ __launch_bounds__(256) void k_gat2_gemm(const float* __restrict__ o1,
    const float* __restrict__ W2, const float* __restrict__ as2, const float* __restrict__ ad2,
    float* __restrict__ h2, float* __restrict__ es2, float* __restrict__ ed2)
{
  __shared__ float At[48][68];
  __shared__ float Ws[48][128];
  int t = threadIdx.x, tx = t & 15, ty = t >> 4;
  int n0 = blockIdx.x * 64;
#pragma unroll
  for (int p = 0; p < 3; ++p){
    int f = t + p * 256;           // 768 float4 = 64 rows x 12
    int node = f / 12, kq = f % 12;
    float4 v = make_float4(0.f, 0.f, 0.f, 0.f);
    if (n0 + node < NN) v = *(const float4*)(o1 + (size_t)(n0 + node) * 48 + kq * 4);
    At[kq * 4 + 0][node] = v.x; At[kq * 4 + 1][node] = v.y;
    At[kq * 4 + 2][node] = v.z; At[kq * 4 + 3][node] = v.w;
  }
#pragma unroll
  for (int p = 0; p < 6; ++p){
    int f = t + p * 256;           // 1536 float4 = 48 rows x 32
    int k = f >> 5, cq = f & 31;
    *(float4*)&Ws[k][cq * 4] = *(const float4*)(W2 + (size_t)k * 128 + cq * 4);
  }
  __syncthreads();
  float acc[4][8] = {};
#pragma unroll 4
  for (int k = 0; k < 48; ++k){
    float4 a  = *(const float4*)&At[k][ty * 4];
    float4 c0 = *(const float4*)&Ws[k][tx * 4];
    float4 c1 = *(const float4*)&Ws[k][tx * 4 + 64];
    float av[4] = {a.x, a.y, a.z, a.w};
    float bv[8] = {c0.x, c0.y, c0.z, c0.w, c1.x, c1.y, c1.z, c1.w};
#pragma unroll
    for (int i = 0; i < 4; ++i)
#pragma unroll
      for (int j = 0; j < 8; ++j)
        acc[i][j] = fmaf(av[i], bv[j], acc[i][j]);
  }
  float asv[8], adv[8];
#pragma unroll
  for (int j = 0; j < 4; ++j){
    asv[j] = as2[tx * 4 + j];      asv[4 + j] = as2[64 + tx * 4 + j];
    adv[j] = ad2[tx * 4 + j];      adv[4 + j] = ad2[64 + tx * 4 + j];
  }
#pragma unroll
  for (int i = 0; i < 4; ++i){
    int gn = n0 + ty * 4 + i;
    float s = 0.f, d = 0.f;
#pragma unroll
    for (int j = 0; j < 8; ++j){ s = fmaf(acc[i][j], asv[j], s); d = fmaf(acc[i][j], adv[j], d); }
#pragma unroll
    for (int off = 1; off < 16; off <<= 1){
      s += __shfl_xor(s, off, 16);
      d += __shfl_xor(d, off, 16);
    }
    if (gn < NN){
      float4 o0 = make_float4(acc[i][0], acc[i][1], acc[i][2], acc[i][3]);
      float4 o1v = make_float4(acc[i][4], acc[i][5], acc[i][6], acc[i][7]);
      *(float4*)(h2 + (size_t)gn * 128 + tx * 4) = o0;
      *(float4*)(h2 + (size_t)gn * 128 + tx * 4 + 64) = o1v;
      if (tx == 0){ es2[gn] = s; ed2[gn] = d; }
    }
  }
}

// ---- GAT2 aggregate: 2 nodes/wave, 32 lanes x float4, unroll-2, fused +b2 + log_softmax ----
__global__ __launch_bounds__(256) void k_gat2_agg(
    const int* __restrict__ csr, const int* __restrict__ row_start,
    const float* __restrict__ es2, const float* __restrict__ ed2,
    const float* __restrict__ h2, const float* __restrict__ b2,
    float* __restrict__ o2)
{
  int wid = (blockIdx.x * 256 + threadIdx.x) >> 6;
  int lane = threadIdx.x & 63;
  int half = lane >> 5, l32 = lane & 31;
  int d = wid * 2 + half;
  if (d >= NN) return;
  int beg = row_start[d], end = row_start[d + 1];
  float edv = ed2[d];
  float m = -INFINITY, sum = 0.f;
  float ax = 0.f, ay = 0.f, az = 0.f, aw = 0.f;
  int i = beg;
  for (; i + 1 < end; i += 2){
    int s0 = csr[i], s1 = csr[i + 1];
    float e0 = lrelu(es2[s0] + edv);
    float e1 = lrelu(es2[s1] + edv);
    float4 v0 = *(const float4*)(h2 + (size_t)s0 * 128 + l32 * 4);
    float4 v1 = *(const float4*)(h2 + (size_t)s1 * 128 + l32 * 4);
    float mn = fmaxf(m, fmaxf(e0, e1));
    float sc = __expf(m - mn), w0 = __expf(e0 - mn), w1 = __expf(e1 - mn);
    sum = sum * sc + w0 + w1;
    ax = ax * sc + v0.x * w0 + v1.x * w1;
    ay = ay * sc + v0.y * w0 + v1.y * w1;
    az = az * sc + v0.z * w0 + v1.z * w1;
    aw = aw * sc + v0.w * w0 + v1.w * w1;
    m = mn;
  }
  if (i < end){
    int s0 = csr[i];
    float e0 = lrelu(es2[s0] + edv);
    float4 v0 = *(const float4*)(h2 + (size_t)s0 * 128 + l32 * 4);
    float mn = fmaxf(m, e0);
    float sc = __expf(m - mn), w0 = __expf(e0 - mn);
    sum = sum * sc + w0;
    ax = ax * sc + v0.x * w0;
    ay = ay * sc + v0.y * w0;
    az = az * sc + v0.z * w0;
    aw = aw * sc + v0.w * w0;
  }
  float inv = 1.f / sum;
  float4 vb = *(const float4*)(b2 + l32 * 4);
  float v0 = ax * inv + vb.x, v1 = ay * inv + vb.y;
  float v2 = az * inv + vb.z, v3 = aw * inv + vb.w;
  float mx = fmaxf(fmaxf(v0, v1), fmaxf(v2, v3));
#pragma unroll
  for (int off = 16; off; off >>= 1) mx = fmaxf(mx, __shfl_xor(mx, off, 32));
  float es = __expf(v0 - mx) + __expf(v1 - mx) + __expf(v2 - mx) + __expf(v3 - mx);
#pragma unroll
  for (int off = 16; off; off >>= 1) es += __shfl_xor(es, off, 32);
  float lse = mx + __logf(es);
  float4 ov = make_float4(v0 - lse, v1 - lse, v2 - lse, v3 - lse);
  *(float4*)(o2 + (size_t)d * 128 + l32 * 4) = ov;
}

// ---- GCN aggregate: 2 nodes/wave, float4 ----
__global__ __launch_bounds__(256) void k_gcn_agg(
    const int* __restrict__ csr, const int* __restrict__ row_start,
    const float* __restrict__ dinv, const float* __restrict__ hg,
    float* __restrict__ og)
{
  int wid = (blockIdx.x * 256 + threadIdx.x) >> 6;
  int lane = threadIdx.x & 63;
  int half = lane >> 5, l32 = lane & 31;
  int d = wid * 2 + half;
  if (d >= NN) return;
  int beg = row_start[d], end = row_start[d + 1];
  float ax = 0.f, ay = 0.f, az = 0.f, aw = 0.f;
  float bx = 0.f, by = 0.f, bz = 0.f, bw = 0.f;
  int i = beg;
  for (; i + 1 < end; i += 2){
    int s0 = csr[i], s1 = csr[i + 1];
    float4 v0 = *(const float4*)(hg + (size_t)s0 * 128 + l32 * 4);
    float4 v1 = *(const float4*)(hg + (size_t)s1 * 128 + l32 * 4);
    ax += v0.x; ay += v0.y; az += v0.z; aw += v0.w;
    bx += v1.x; by += v1.y; bz += v1.z; bw += v1.w;
  }
  if (i < end){
    int s0 = csr[i];
    float4 v0 = *(const float4*)(hg + (size_t)s0 * 128 + l32 * 4);
    ax += v0.x; ay += v0.y; az += v0.z; aw += v0.w;
  }
  float dd = dinv[d];
  float4 ov = make_float4((ax + bx) * dd, (ay + by) * dd, (az + bz) * dd, (aw + bw) * dd);
  *(float4*)(og + (size_t)d * 128 + l32 * 4) = ov;
}

// ---- 128x128 per-node GEMM, fp32 tiled; PRE: relu(in+bpre); POST: +bpost; SCALE: *dinv[row] ----
template<int PRE, int POST, int SCALE>
__global__ __launch_bounds__(256) void k_gemm128(const float* __restrict__ in,
    const float* __restrict__ W, const float* __restrict__ bpre,
    const float* __restrict__ bpost, const float* __restrict__ dinv,
    float* __restrict__ out)
{
  __shared__ float At[32][68];
  __shared__ float Ws[32][128];
  int t = threadIdx.x, tx = t & 15, ty = t >> 4;
  int n0 = blockIdx.x * 64;
  float acc[4][8] = {};
  for (int kt = 0; kt < 128; kt += 32){
    __syncthreads();
#pragma unroll
    for (int p = 0; p < 2; ++p){
      int f = t + p * 256;            // 512 float4 = 64 rows x 8
      int node = f >> 3, kq = f & 7;
      float4 v = make_float4(0.f, 0.f, 0.f, 0.f);
      if (n0 + node < NN){
        v = *(const float4*)(in + (size_t)(n0 + node) * 128 + kt + kq * 4);
        if (PRE){
          const float* bp = bpre + kt + kq * 4;
          v.x = fmaxf(v.x + bp[0], 0.f); v.y = fmaxf(v.y + bp[1], 0.f);
          v.z = fmaxf(v.z + bp[2], 0.f); v.w = fmaxf(v.w + bp[3], 0.f);
        }
      }
      At[kq * 4 + 0][node] = v.x; At[kq * 4 + 1][node] = v.y;
      At[kq * 4 + 2][node] = v.z; At[kq * 4 + 3][node] = v.w;
    }
#pragma unroll
    for (int p = 0; p < 4; ++p){
      int f = t + p * 256;            // 1024 float4 = 32 rows x 32
      int k = f >> 5, cq = f & 31;
      *(float4*)&Ws[k][cq * 4] = *(const float4*)(W + (size_t)(kt + k) * 128 + cq * 4);
    }
    __syncthreads();
#pragma unroll 4
    for (int k = 0; k < 32; ++k){
      float4 a  = *(const float4*)&At[k][ty * 4];
      float4 c0 = *(const float4*)&Ws[k][tx * 4];
      float4 c1 = *(const float4*)&Ws[k][tx * 4 + 64];
      float av[4] = {a.x, a.y, a.z, a.w};
      float bv[8] = {c0.x, c0.y, c0.z, c0.w, c1.x, c1.y, c1.z, c1.w};
#pragma unroll
      for (int i = 0; i < 4; ++i)
#pragma unroll
        for (int j = 0; j < 8; ++j)
          acc[i][j] = fmaf(av[i], bv[j], acc[i][j]);
    }
  }
#pragma unroll
  for (int i = 0; i < 4; ++i){
    int gn = n0 + ty * 4 + i;
    if (gn < NN){
      float sc = SCALE ? dinv[gn] : 1.f;
      float4 o0, o1v;
      o0.x  = (acc[i][0] + (POST ? bpost[tx * 4 + 0] : 0.f)) * sc;
      o0.y  = (acc[i][1] + (POST ? bpost[tx * 4 + 1] : 0.f)) * sc;
      o0.z  = (acc[i][2] + (POST ? bpost[tx * 4 + 2] : 0.f)) * sc;
      o0.w  = (acc[i][3] + (POST ? bpost[tx * 4 + 3] : 0.f)) * sc;
      o1v.x = (acc[i][4] + (POST ? bpost[64 + tx * 4 + 0] : 0.f)) * sc;
      o1v.y = (acc[i][5] + (POST ? bpost[64 + tx * 4 + 1] : 0.f)) * sc;
      o1v.z = (acc[i][6] + (POST ? bpost[64 + tx * 4 + 2] : 0.f)) * sc;
      o1v.w = (acc[i][7] + (POST ? bpost[64 + tx * 4 + 3] : 0.f)) * sc;
      *(float4*)(out + (size_t)gn * 128 + tx * 4) = o0;
      *(float4*)(out + (size_t)gn * 128 + tx * 4 + 64) = o1v;
    }
  }
}

extern "C" void kernel_launch(void* const* d_in, const int* in_sizes, int n_in,
                              void* d_out, int out_size, void* d_ws, size_t ws_size,
                              hipStream_t stream)
{
  const float* x   = (const float*)d_in[0];
  const int*   ei  = (const int*)d_in[1];
  const float* W1  = (const float*)d_in[2];
  const float* as1 = (const float*)d_in[3];
  const float* ad1 = (const float*)d_in[4];
  const float* b1  = (const float*)d_in[5];
  const float* W2  = (const float*)d_in[6];
  const float* as2 = (const float*)d_in[7];
  const float* ad2 = (const float*)d_in[8];
  const float* b2  = (const float*)d_in[9];
  const float* Wg  = (const float*)d_in[10];
  const float* bg  = (const float*)d_in[11];
  const float* Wl  = (const float*)d_in[12];
  const float* bl  = (const float*)d_in[13];
  float* out = (float*)d_out;

  float* ws = (float*)d_ws;
  const size_t n = NN;
  float* h1   = ws;                 // 48N
  float* h2   = ws + 48 * n;        // 128N (reused as hg)
  float* o1   = ws + 176 * n;       // 48N
  float* o2   = ws + 224 * n;       // 128N (lsm out; later reused as og)
  float* es1  = ws + 352 * n;       // 3N
  float* ed1  = ws + 355 * n;       // 3N
  float* es2  = ws + 358 * n;       // N
  float* ed2  = ws + 359 * n;       // N
  float* dinv = ws + 360 * n;       // N
  int* ints   = (int*)(ws + 361 * n);
  int* deg_i     = ints;            // N   (zeroed)
  int* cur       = ints + n;        // N   (zeroed)
  int* row_start = ints + 2 * n;    // N+1
  int* csr       = ints + 3 * n + 1;// ET
  int* bsum      = ints + 3 * n + 1 + ET;      // NB
  int* boff      = ints + 3 * n + 1 + ET + NB; // NB
  float* og = o2;                   // overwrite o2 after gemm128<Wg> consumed it

  hipMemsetAsync(deg_i, 0, 2 * n * sizeof(int), stream);

  const int egrid = (ET + 255) / 256;
  const int wgrid = (NN * 64) / 256;        // one wave per node
  const int hgrid = (NN / 2 * 64) / 256;    // two nodes per wave
  k_hist<<<egrid, 256, 0, stream>>>(ei, deg_i);
  k_scan_part<<<NB, 256, 0, stream>>>(deg_i, bsum);
  k_scan_top<<<1, 256, 0, stream>>>(bsum, boff);
  k_scan_fin<<<NB, 256, 0, stream>>>(deg_i, boff, row_start, dinv);
  k_fill<<<egrid, 256, 0, stream>>>(ei, row_start, cur, csr);
  k_gat1_gemm<<<(NN + 63) / 64, 256, 0, stream>>>(x, W1, as1, ad1, h1, es1, ed1);
  k_gat1_agg<<<wgrid, 256, 0, stream>>>(csr, row_start, es1, ed1, h1, b1, o1);
  k_gat2_gemm<<<(NN + 63) / 64, 256, 0, stream>>>(o1, W2, as2, ad2, h2, es2, ed2);
  k_gat2_agg<<<hgrid, 256, 0, stream>>>(csr, row_start, es2, ed2, h2, b2, o2);
  k_gemm128<0, 0, 1><<<(NN + 63) / 64, 256, 0, stream>>>(o2, Wg, nullptr, nullptr, dinv, h2);
  k_gcn_agg<<<hgrid, 256, 0, stream>>>(csr, row_start, dinv, h2, og);
  k_gemm128<1, 1, 0><<<(NN + 63) / 64, 256, 0, stream>>>(og, Wl, bg, bl, nullptr, out);
}